// Round 1
// baseline (1411.717 us; speedup 1.0000x reference)
//
#include <hip/hip_runtime.h>
#include <hip/hip_bf16.h>
#include <math.h>

typedef __attribute__((ext_vector_type(8))) short bf16x8;
typedef __attribute__((ext_vector_type(4))) float f32x4;

__device__ __forceinline__ float b2f(unsigned short u) {
    unsigned int v = ((unsigned int)u) << 16;
    return __uint_as_float(v);
}
__device__ __forceinline__ unsigned short f2b(float f) {
    __hip_bfloat16 h = __float2bfloat16(f);
    return *reinterpret_cast<unsigned short*>(&h);
}

// ---------------- prep: transpose conv weights to k-contiguous ----------------
// w1 [32][256] -> wt1 [256][32]; w2 [64][512] -> wt2 [512][64]; w3 [64][576] -> wt3 [576][64]
__global__ __launch_bounds__(256) void prep_convw(
    const float* __restrict__ w1, const float* __restrict__ w2, const float* __restrict__ w3,
    float* __restrict__ wt1, float* __restrict__ wt2, float* __restrict__ wt3) {
    int tid = blockIdx.x * 256 + threadIdx.x;
    if (tid < 8192) {
        int k = tid >> 8, r = tid & 255;
        wt1[r * 32 + k] = w1[tid];
    } else if (tid < 8192 + 32768) {
        int i = tid - 8192;
        int k = i >> 9, r = i & 511;
        wt2[r * 64 + k] = w2[i];
    } else if (tid < 8192 + 32768 + 36864) {
        int i = tid - 40960;
        int k = i / 576, r = i % 576;
        wt3[r * 64 + k] = w3[i];
    }
}

// ---------------- prep: expert weights [e][d][h] -> bf16 [e][h][d] ----------------
__global__ __launch_bounds__(256) void prep_ewT(
    const float* __restrict__ ew1, const float* __restrict__ ew2,
    unsigned short* __restrict__ t1, unsigned short* __restrict__ t2) {
    __shared__ float tile[32][33];
    int z = blockIdx.z;
    int e = z % 6;
    const float* src = (z < 6) ? (ew1 + e * 262144) : (ew2 + e * 262144);
    unsigned short* dst = (z < 6) ? (t1 + e * 262144) : (t2 + e * 262144);
    int d0 = blockIdx.y * 32;
    int h0 = blockIdx.x * 32;
    int tx = threadIdx.x, ty = threadIdx.y;
#pragma unroll
    for (int j = 0; j < 4; j++)
        tile[ty + j * 8][tx] = src[(d0 + ty + j * 8) * 512 + h0 + tx];
    __syncthreads();
#pragma unroll
    for (int j = 0; j < 4; j++)
        dst[(h0 + ty + j * 8) * 512 + (d0 + tx)] = f2b(tile[tx][ty + j * 8]);
}

// ---------------- conv1: 4ch 84x84 -> 32ch 20x20, 8x8 s4, fp32 ----------------
__global__ __launch_bounds__(256) void conv1_k(
    const float* __restrict__ x, const float* __restrict__ wt1,
    const float* __restrict__ b1, float* __restrict__ out) {
    __shared__ float xs[4 * 44 * 84];  // 57.75 KB
    int n = blockIdx.x >> 1, h = blockIdx.x & 1;
    int r0 = h * 40;
    for (int idx = threadIdx.x; idx < 14784; idx += 256) {
        int c = idx / 3696, rem = idx % 3696;
        int r = rem / 84, col = rem % 84;
        xs[idx] = x[((n * 4 + c) * 84 + (r0 + r)) * 84 + col];
    }
    __syncthreads();
    int t = threadIdx.x;
    if (t < 200) {
        int oy = t / 20, ox = t % 20;
        float acc[32];
#pragma unroll
        for (int k = 0; k < 32; k++) acc[k] = b1[k];
        for (int c = 0; c < 4; c++)
            for (int ky = 0; ky < 8; ky++) {
                const float* xrow = &xs[c * 3696 + (oy * 4 + ky) * 84 + ox * 4];
                const float* wr = &wt1[((c * 8 + ky) * 8) * 32];
#pragma unroll
                for (int kx = 0; kx < 8; kx++) {
                    float xv = xrow[kx];
#pragma unroll
                    for (int k = 0; k < 32; k++) acc[k] += xv * wr[kx * 32 + k];
                }
            }
        int oyg = h * 10 + oy;
#pragma unroll
        for (int k = 0; k < 32; k++)
            out[(n * 32 + k) * 400 + oyg * 20 + ox] = fmaxf(acc[k], 0.f);
    }
}

// ---------------- conv2: 32ch 20x20 -> 64ch 9x9, 4x4 s2, fp32 ----------------
__global__ __launch_bounds__(256) void conv2_k(
    const float* __restrict__ in, const float* __restrict__ wt2,
    const float* __restrict__ b2, float* __restrict__ out) {
    int tid = blockIdx.x * 256 + threadIdx.x;
    if (tid >= 2048 * 81) return;
    int n = tid / 81, p = tid % 81;
    int oy = p / 9, ox = p % 9;
    const float* xn = in + n * 32 * 400;
    float acc[64];
#pragma unroll
    for (int k = 0; k < 64; k++) acc[k] = b2[k];
    for (int c = 0; c < 32; c++)
        for (int ky = 0; ky < 4; ky++) {
            const float* xr = xn + c * 400 + (oy * 2 + ky) * 20 + ox * 2;
            const float* wr = wt2 + ((c * 4 + ky) * 4) * 64;
#pragma unroll
            for (int kx = 0; kx < 4; kx++) {
                float xv = xr[kx];
#pragma unroll
                for (int k = 0; k < 64; k++) acc[k] += xv * wr[kx * 64 + k];
            }
        }
    float* o = out + n * 64 * 81 + p;
#pragma unroll
    for (int k = 0; k < 64; k++) o[k * 81] = fmaxf(acc[k], 0.f);
}

// ---------------- conv3: 64ch 9x9 -> 64ch 7x7, 3x3 s1, fp32; writes flattened [n][3136] ----------------
__global__ __launch_bounds__(256) void conv3_k(
    const float* __restrict__ in, const float* __restrict__ wt3,
    const float* __restrict__ b3, float* __restrict__ out) {
    int tid = blockIdx.x * 256 + threadIdx.x;
    if (tid >= 2048 * 49) return;
    int n = tid / 49, p = tid % 49;
    int oy = p / 7, ox = p % 7;
    const float* xn = in + n * 64 * 81;
    float acc[64];
#pragma unroll
    for (int k = 0; k < 64; k++) acc[k] = b3[k];
    for (int c = 0; c < 64; c++)
        for (int ky = 0; ky < 3; ky++) {
            const float* xr = xn + c * 81 + (oy + ky) * 9 + ox;
            const float* wr = wt3 + ((c * 3 + ky) * 3) * 64;
#pragma unroll
            for (int kx = 0; kx < 3; kx++) {
                float xv = xr[kx];
#pragma unroll
                for (int k = 0; k < 64; k++) acc[k] += xv * wr[kx * 64 + k];
            }
        }
    float* o = out + n * 3136 + p;
#pragma unroll
    for (int k = 0; k < 64; k++) o[k * 49] = fmaxf(acc[k], 0.f);
}

// ---------------- fc: [2048,3136] x [3136,512] + bias, relu, fp32 (also bf16 copy) ----------------
__global__ __launch_bounds__(256) void fc_k(
    const float* __restrict__ A, const float* __restrict__ Bw,
    const float* __restrict__ bias, float* __restrict__ Cf, unsigned short* __restrict__ Cb) {
    __shared__ float As[16][68];  // [k][m], padded
    __shared__ float Bs[16][68];  // [k][n], padded
    int t = threadIdx.x;
    int tx = t & 15, ty = t >> 4;
    int m0 = blockIdx.x * 64, n0 = blockIdx.y * 64;
    float acc[4][4];
#pragma unroll
    for (int i = 0; i < 4; i++)
#pragma unroll
        for (int j = 0; j < 4; j++) acc[i][j] = 0.f;
    int am = t >> 2, ak = (t & 3) * 4;
    int bk = t >> 4, bn = (t & 15) * 4;
    for (int k0 = 0; k0 < 3136; k0 += 16) {
        float4 av = *(const float4*)&A[(long)(m0 + am) * 3136 + k0 + ak];
        float4 bv = *(const float4*)&Bw[(long)(k0 + bk) * 512 + n0 + bn];
        As[ak + 0][am] = av.x;
        As[ak + 1][am] = av.y;
        As[ak + 2][am] = av.z;
        As[ak + 3][am] = av.w;
        *(float4*)&Bs[bk][bn] = bv;
        __syncthreads();
#pragma unroll
        for (int kk = 0; kk < 16; kk++) {
            float4 a = *(const float4*)&As[kk][ty * 4];
            float4 b = *(const float4*)&Bs[kk][tx * 4];
            float a4[4] = {a.x, a.y, a.z, a.w};
            float b4[4] = {b.x, b.y, b.z, b.w};
#pragma unroll
            for (int i = 0; i < 4; i++)
#pragma unroll
                for (int j = 0; j < 4; j++) acc[i][j] += a4[i] * b4[j];
        }
        __syncthreads();
    }
#pragma unroll
    for (int i = 0; i < 4; i++) {
        int row = m0 + ty * 4 + i;
#pragma unroll
        for (int j = 0; j < 4; j++) {
            int col = n0 + tx * 4 + j;
            float v = fmaxf(acc[i][j] + bias[col], 0.f);
            Cf[row * 512 + col] = v;
            Cb[row * 512 + col] = f2b(v);
        }
    }
}

// ---------------- gate: logits, top-2, renormalized probs (fp32, exact) ----------------
__global__ __launch_bounds__(256) void gate_k(
    const float* __restrict__ f, const float* __restrict__ gw, const float* __restrict__ gb,
    int* __restrict__ topi, float* __restrict__ topp) {
    int wave = threadIdx.x >> 6, lane = threadIdx.x & 63;
    int row = blockIdx.x * 4 + wave;
    float fv[8];
#pragma unroll
    for (int j = 0; j < 8; j++) fv[j] = f[row * 512 + lane + 64 * j];
    float lg[6];
#pragma unroll
    for (int e = 0; e < 6; e++) {
        float a = 0.f;
#pragma unroll
        for (int j = 0; j < 8; j++) a += fv[j] * gw[(lane + 64 * j) * 6 + e];
#pragma unroll
        for (int off = 32; off > 0; off >>= 1) a += __shfl_xor(a, off, 64);
        lg[e] = a + gb[e];
    }
    if (lane == 0) {
        int i1 = 0;
        float v1 = lg[0];
#pragma unroll
        for (int e = 1; e < 6; e++)
            if (lg[e] > v1) { v1 = lg[e]; i1 = e; }
        int i2 = (i1 == 0) ? 1 : 0;
        float v2 = lg[i2];
#pragma unroll
        for (int e = 0; e < 6; e++)
            if (e != i1 && lg[e] > v2) { v2 = lg[e]; i2 = e; }
        float pa = 1.f / (1.f + expf(v2 - v1));  // softmax top-2 renorm, exact
        topi[row * 2] = i1;
        topi[row * 2 + 1] = i2;
        topp[row * 2] = pa;
        topp[row * 2 + 1] = 1.f - pa;
    }
}

// ---------------- expert GEMM: bf16 MFMA 16x16x32, 64x64 tile, relu, per-expert ----------------
__global__ __launch_bounds__(256) void moe_gemm(
    const unsigned short* __restrict__ A, long aStride,
    const unsigned short* __restrict__ Bt, const float* __restrict__ bias,
    unsigned short* __restrict__ C) {
    int e = blockIdx.z;
    const unsigned short* Ae = A + (long)e * aStride;
    const unsigned short* Be = Bt + (long)e * 262144;
    const float* be = bias + e * 512;
    unsigned short* Ce = C + (long)e * 2048 * 512;
    __shared__ unsigned short As[64 * 40];  // [m][k] pad 40
    __shared__ unsigned short Bs[64 * 40];  // [n][k] pad 40
    int t = threadIdx.x;
    int m0 = blockIdx.x * 64, n0 = blockIdx.y * 64;
    int wave = t >> 6, lane = t & 63;
    int l16 = lane & 15, quad = lane >> 4;
    int wm = (wave & 1) * 32, wn = (wave >> 1) * 32;
    int sm = t >> 2, sk = (t & 3) * 8;
    f32x4 acc[2][2];
#pragma unroll
    for (int i = 0; i < 2; i++)
#pragma unroll
        for (int j = 0; j < 2; j++)
#pragma unroll
            for (int r = 0; r < 4; r++) acc[i][j][r] = 0.f;
    for (int k0 = 0; k0 < 512; k0 += 32) {
        bf16x8 av = *(const bf16x8*)&Ae[(long)(m0 + sm) * 512 + k0 + sk];
        bf16x8 bv = *(const bf16x8*)&Be[(long)(n0 + sm) * 512 + k0 + sk];
        *(bf16x8*)&As[sm * 40 + sk] = av;
        *(bf16x8*)&Bs[sm * 40 + sk] = bv;
        __syncthreads();
        bf16x8 af0 = *(const bf16x8*)&As[(wm + l16) * 40 + quad * 8];
        bf16x8 af1 = *(const bf16x8*)&As[(wm + 16 + l16) * 40 + quad * 8];
        bf16x8 bf0 = *(const bf16x8*)&Bs[(wn + l16) * 40 + quad * 8];
        bf16x8 bf1 = *(const bf16x8*)&Bs[(wn + 16 + l16) * 40 + quad * 8];
        acc[0][0] = __builtin_amdgcn_mfma_f32_16x16x32_bf16(af0, bf0, acc[0][0], 0, 0, 0);
        acc[0][1] = __builtin_amdgcn_mfma_f32_16x16x32_bf16(af0, bf1, acc[0][1], 0, 0, 0);
        acc[1][0] = __builtin_amdgcn_mfma_f32_16x16x32_bf16(af1, bf0, acc[1][0], 0, 0, 0);
        acc[1][1] = __builtin_amdgcn_mfma_f32_16x16x32_bf16(af1, bf1, acc[1][1], 0, 0, 0);
        __syncthreads();
    }
#pragma unroll
    for (int mt = 0; mt < 2; mt++)
#pragma unroll
        for (int nt = 0; nt < 2; nt++) {
            int col = n0 + wn + nt * 16 + l16;
            float bcol = be[col];
#pragma unroll
            for (int r = 0; r < 4; r++) {
                int row = m0 + wm + mt * 16 + quad * 4 + r;
                float v = fmaxf(acc[mt][nt][r] + bcol, 0.f);
                Ce[(long)row * 512 + col] = f2b(v);
            }
        }
}

// ---------------- final expert layer (512->12) + weighted combine, selected experts only ----------------
__global__ __launch_bounds__(256) void combine_k(
    const unsigned short* __restrict__ h2, const float* __restrict__ w3,
    const float* __restrict__ b3, const int* __restrict__ topi,
    const float* __restrict__ topp, float* __restrict__ out) {
    int tid = blockIdx.x * 256 + threadIdx.x;
    if (tid >= 2048 * 12) return;
    int b = tid / 12, a = tid % 12;
    float r = 0.f;
#pragma unroll
    for (int j = 0; j < 2; j++) {
        int e = topi[b * 2 + j];
        float p = topp[b * 2 + j];
        const unsigned short* h = h2 + ((long)e * 2048 + b) * 512;
        const float* w = w3 + e * 512 * 12 + a;
        float acc = b3[e * 12 + a];
#pragma unroll 4
        for (int k = 0; k < 512; k++) acc += b2f(h[k]) * w[k * 12];
        r += p * acc;
    }
    out[tid] = r;
}

extern "C" void kernel_launch(void* const* d_in, const int* in_sizes, int n_in,
                              void* d_out, int out_size, void* d_ws, size_t ws_size,
                              hipStream_t stream) {
    const float* x   = (const float*)d_in[0];
    const float* c1w = (const float*)d_in[1];
    const float* c1b = (const float*)d_in[2];
    const float* c2w = (const float*)d_in[3];
    const float* c2b = (const float*)d_in[4];
    const float* c3w = (const float*)d_in[5];
    const float* c3b = (const float*)d_in[6];
    const float* fcw = (const float*)d_in[7];
    const float* fcb = (const float*)d_in[8];
    const float* gw  = (const float*)d_in[9];
    const float* gb  = (const float*)d_in[10];
    const float* ew1 = (const float*)d_in[11];
    const float* eb1 = (const float*)d_in[12];
    const float* ew2 = (const float*)d_in[13];
    const float* eb2 = (const float*)d_in[14];
    const float* ew3 = (const float*)d_in[15];
    const float* eb3 = (const float*)d_in[16];

    char* ws = (char*)d_ws;
    float* c1o = (float*)(ws + 0L);                       // 2048*32*400 f32 = 104857600 B
    float* c2o = (float*)(ws + 104857600L);               // 2048*64*81 f32  = 42467328 B
    float* f3  = (float*)(ws + 147324928L);               // 2048*3136 f32   = 25690112 B
    float* f   = (float*)(ws + 173015040L);               // 2048*512 f32    = 4194304 B
    unsigned short* fb = (unsigned short*)(ws + 177209344L);   // bf16 f     = 2097152 B
    unsigned short* h1 = (unsigned short*)(ws + 179306496L);   // 6*2048*512 = 12582912 B
    unsigned short* h2 = (unsigned short*)(ws + 191889408L);   //            = 12582912 B
    int*   topi = (int*)(ws + 204472320L);                //             = 16384 B
    float* topp = (float*)(ws + 204488704L);              //             = 16384 B
    float* wt1  = (float*)(ws + 204505088L);              //             = 32768 B
    float* wt2  = (float*)(ws + 204537856L);              //             = 131072 B
    float* wt3  = (float*)(ws + 204668928L);              //             = 147456 B
    unsigned short* ew1t = (unsigned short*)(ws + 204816384L); //         = 3145728 B
    unsigned short* ew2t = (unsigned short*)(ws + 207962112L); //         = 3145728 B
    float* out = (float*)d_out;

    hipLaunchKernelGGL(prep_convw, dim3(304), dim3(256), 0, stream, c1w, c2w, c3w, wt1, wt2, wt3);
    hipLaunchKernelGGL(prep_ewT, dim3(16, 16, 12), dim3(32, 8), 0, stream, ew1, ew2, ew1t, ew2t);
    hipLaunchKernelGGL(conv1_k, dim3(4096), dim3(256), 0, stream, x, wt1, c1b, c1o);
    hipLaunchKernelGGL(conv2_k, dim3(648), dim3(256), 0, stream, c1o, wt2, c2b, c2o);
    hipLaunchKernelGGL(conv3_k, dim3(392), dim3(256), 0, stream, c2o, wt3, c3b, f3);
    hipLaunchKernelGGL(fc_k, dim3(32, 8), dim3(256), 0, stream, f3, fcw, fcb, f, fb);
    hipLaunchKernelGGL(gate_k, dim3(512), dim3(256), 0, stream, f, gw, gb, topi, topp);
    hipLaunchKernelGGL(moe_gemm, dim3(32, 8, 6), dim3(256), 0, stream, fb, 0L, ew1t, eb1, h1);
    hipLaunchKernelGGL(moe_gemm, dim3(32, 8, 6), dim3(256), 0, stream, h1, 1048576L, ew2t, eb2, h2);
    hipLaunchKernelGGL(combine_k, dim3(96), dim3(256), 0, stream, h2, ew3, eb3, topi, topp, out);
}

// Round 2
// 852.434 us; speedup vs baseline: 1.6561x; 1.6561x over previous
//
#include <hip/hip_runtime.h>
#include <hip/hip_bf16.h>
#include <math.h>

typedef __attribute__((ext_vector_type(8))) short bf16x8;
typedef __attribute__((ext_vector_type(4))) float f32x4;

__device__ __forceinline__ float b2f(unsigned short u) {
    unsigned int v = ((unsigned int)u) << 16;
    return __uint_as_float(v);
}
__device__ __forceinline__ unsigned short f2b(float f) {
    __hip_bfloat16 h = __float2bfloat16(f);
    return *reinterpret_cast<unsigned short*>(&h);
}

// ============ prep: conv weights ============
// w1 [32][4][8][8] -> w1r[ky][c][kx][k32] fp32
// w2 [64][32][4][4] -> w2h/l[(ky*4+kx)*64 + n][c32] bf16 hi/lo
// w3 [64][64][3][3] -> w3h/l[((ky*3+kx)*2+ch)*64 + n][cc32] bf16 hi/lo
__global__ __launch_bounds__(256) void prep_w(
    const float* __restrict__ w1, const float* __restrict__ w2, const float* __restrict__ w3,
    float* __restrict__ w1r, unsigned short* __restrict__ w2h, unsigned short* __restrict__ w2l,
    unsigned short* __restrict__ w3h, unsigned short* __restrict__ w3l) {
    int tid = blockIdx.x * 256 + threadIdx.x;
    if (tid < 8192) {
        int k = tid >> 8, r = tid & 255;
        int c = r >> 6, ky = (r >> 3) & 7, kx = r & 7;
        w1r[((ky * 4 + c) * 8 + kx) * 32 + k] = w1[tid];
    } else if (tid < 8192 + 32768) {
        int i = tid - 8192;
        int n = i >> 9, r = i & 511;
        int c = r >> 4, ky = (r >> 2) & 3, kx = r & 3;
        float v = w2[i];
        unsigned short h = f2b(v);
        int d = ((ky * 4 + kx) * 64 + n) * 32 + c;
        w2h[d] = h;
        w2l[d] = f2b(v - b2f(h));
    } else if (tid < 8192 + 32768 + 36864) {
        int i = tid - 40960;
        int n = i / 576, r = i - n * 576;
        int c = r / 9, s = r - c * 9;
        int ky = s / 3, kx = s - ky * 3;
        float v = w3[i];
        unsigned short h = f2b(v);
        int d = (((ky * 3 + kx) * 2 + (c >> 5)) * 64 + n) * 32 + (c & 31);
        w3h[d] = h;
        w3l[d] = f2b(v - b2f(h));
    }
}

// ============ prep: fc weights: fc_w[(c*49+p)*512+n] -> fcw[n][ (p*64+c) ] hi/lo ============
__global__ __launch_bounds__(256) void prep_fcw(
    const float* __restrict__ fw, unsigned short* __restrict__ h, unsigned short* __restrict__ l) {
    __shared__ float tile[64][65];
    int k0 = blockIdx.x * 64;  // k' base (49 blocks)
    int n0 = blockIdx.y * 64;  // 8 blocks
    int tx = threadIdx.x & 63, ty = threadIdx.x >> 6;
#pragma unroll
    for (int j = 0; j < 16; j++) {
        int kk = ty + j * 4;
        int kp = k0 + kk;
        int p = kp >> 6, c = kp & 63;
        tile[kk][tx] = fw[(c * 49 + p) * 512 + n0 + tx];
    }
    __syncthreads();
#pragma unroll
    for (int j = 0; j < 16; j++) {
        int r = ty + j * 4;
        float v = tile[tx][r];
        unsigned short hh = f2b(v);
        long d = (long)(n0 + r) * 3136 + k0 + tx;
        h[d] = hh;
        l[d] = f2b(v - b2f(hh));
    }
}

// ============ prep: expert weights [e][d][h] -> bf16 [e][h][d] (unchanged, verified) ============
__global__ __launch_bounds__(256) void prep_ewT(
    const float* __restrict__ ew1, const float* __restrict__ ew2,
    unsigned short* __restrict__ t1, unsigned short* __restrict__ t2) {
    __shared__ float tile[32][33];
    int z = blockIdx.z;
    int e = z % 6;
    const float* src = (z < 6) ? (ew1 + e * 262144) : (ew2 + e * 262144);
    unsigned short* dst = (z < 6) ? (t1 + e * 262144) : (t2 + e * 262144);
    int d0 = blockIdx.y * 32;
    int h0 = blockIdx.x * 32;
    int tx = threadIdx.x, ty = threadIdx.y;
#pragma unroll
    for (int j = 0; j < 4; j++)
        tile[ty + j * 8][tx] = src[(d0 + ty + j * 8) * 512 + h0 + tx];
    __syncthreads();
#pragma unroll
    for (int j = 0; j < 4; j++)
        dst[(h0 + ty + j * 8) * 512 + (d0 + tx)] = f2b(tile[tx][ty + j * 8]);
}

// ============ conv1: fp32 register-resident, 1 px/thread, out NHWC bf16 hi/lo ============
__global__ __launch_bounds__(256) void conv1_k(
    const float* __restrict__ x, const float* __restrict__ w1r,
    const float* __restrict__ b1, unsigned short* __restrict__ yhi,
    unsigned short* __restrict__ ylo) {
    int px = blockIdx.x * 256 + threadIdx.x;  // 819200 total
    int n = px / 400;
    int rem = px - n * 400;
    int oy = rem / 20;
    int ox = rem - oy * 20;
    const float* xb = x + (long)n * 28224 + oy * 4 * 84 + ox * 4;
    float acc[32];
#pragma unroll
    for (int k = 0; k < 32; k++) acc[k] = b1[k];
    for (int ky = 0; ky < 8; ky++) {
        const float* xr = xb + ky * 84;
        float4 xv[8];
#pragma unroll
        for (int c = 0; c < 4; c++) {
            xv[c * 2]     = *(const float4*)(xr + c * 7056);
            xv[c * 2 + 1] = *(const float4*)(xr + c * 7056 + 4);
        }
        const float* wk = w1r + ky * 1024;
#pragma unroll
        for (int c = 0; c < 4; c++) {
            float xs[8] = {xv[c * 2].x,     xv[c * 2].y,     xv[c * 2].z,     xv[c * 2].w,
                           xv[c * 2 + 1].x, xv[c * 2 + 1].y, xv[c * 2 + 1].z, xv[c * 2 + 1].w};
#pragma unroll
            for (int kx = 0; kx < 8; kx++) {
                float xsv = xs[kx];
                const float* w = wk + (c * 8 + kx) * 32;
#pragma unroll
                for (int k = 0; k < 32; k++) acc[k] = fmaf(xsv, w[k], acc[k]);
            }
        }
    }
    long o = (long)px * 32;
#pragma unroll
    for (int g = 0; g < 4; g++) {
        bf16x8 hv, lv;
#pragma unroll
        for (int j = 0; j < 8; j++) {
            float v = fmaxf(acc[g * 8 + j], 0.f);
            unsigned short h = f2b(v);
            hv[j] = (short)h;
            lv[j] = (short)f2b(v - b2f(h));
        }
        *(bf16x8*)(yhi + o + g * 8) = hv;
        *(bf16x8*)(ylo + o + g * 8) = lv;
    }
}

// ============ conv as implicit-GEMM MFMA, split-bf16 (hi*hi + hi*lo + lo*hi) ============
// X NHWC [B][IH][IW][C] hi/lo; W [KH*KW*(C/32)][64][32] hi/lo; Y NHWC [B][OH][OW][64] hi/lo
template <int C, int IH, int IW, int OH, int OW, int S, int KH, int KW>
__global__ __launch_bounds__(256) void convm_k(
    const unsigned short* __restrict__ xhi, const unsigned short* __restrict__ xlo,
    const unsigned short* __restrict__ whi, const unsigned short* __restrict__ wlo,
    const float* __restrict__ bias,
    unsigned short* __restrict__ yhi, unsigned short* __restrict__ ylo) {
    constexpr int CH = C / 32;
    constexpr int NCHUNK = KH * KW * CH;
    __shared__ unsigned short Ah[256][40], Al[256][40], Bh[64][40], Bl[64][40];
    int t = threadIdx.x;
    int px = blockIdx.x * 256 + t;
    int n = px / (OH * OW);
    int rem = px - n * (OH * OW);
    int oy = rem / OW;
    int ox = rem - oy * OW;
    const long xoff = (((long)n * IH + oy * S) * IW + ox * S) * C;
    int wave = t >> 6, lane = t & 63, l16 = lane & 15, quad = lane >> 4;
    int br = t >> 2, bc = (t & 3) * 8;
    f32x4 acc[4][4];
#pragma unroll
    for (int i = 0; i < 4; i++)
#pragma unroll
        for (int j = 0; j < 4; j++)
#pragma unroll
            for (int r = 0; r < 4; r++) acc[i][j][r] = 0.f;
    for (int ck = 0; ck < NCHUNK; ck++) {
        int kyx = ck / CH;
        int ch = ck - kyx * CH;
        int ky = kyx / KW, kx = kyx - ky * KW;
        long a_src = xoff + ((ky * IW + kx) * C + ch * 32);
#pragma unroll
        for (int j = 0; j < 4; j++) {
            *(bf16x8*)&Ah[t][j * 8] = *(const bf16x8*)(xhi + a_src + j * 8);
            *(bf16x8*)&Al[t][j * 8] = *(const bf16x8*)(xlo + a_src + j * 8);
        }
        long b_src = (long)ck * 2048 + br * 32 + bc;
        *(bf16x8*)&Bh[br][bc] = *(const bf16x8*)(whi + b_src);
        *(bf16x8*)&Bl[br][bc] = *(const bf16x8*)(wlo + b_src);
        __syncthreads();
        bf16x8 ah[4], al[4], bh[4], bl[4];
#pragma unroll
        for (int i = 0; i < 4; i++) {
            ah[i] = *(const bf16x8*)&Ah[wave * 64 + i * 16 + l16][quad * 8];
            al[i] = *(const bf16x8*)&Al[wave * 64 + i * 16 + l16][quad * 8];
            bh[i] = *(const bf16x8*)&Bh[i * 16 + l16][quad * 8];
            bl[i] = *(const bf16x8*)&Bl[i * 16 + l16][quad * 8];
        }
#pragma unroll
        for (int i = 0; i < 4; i++)
#pragma unroll
            for (int j = 0; j < 4; j++) {
                acc[i][j] = __builtin_amdgcn_mfma_f32_16x16x32_bf16(ah[i], bh[j], acc[i][j], 0, 0, 0);
                acc[i][j] = __builtin_amdgcn_mfma_f32_16x16x32_bf16(ah[i], bl[j], acc[i][j], 0, 0, 0);
                acc[i][j] = __builtin_amdgcn_mfma_f32_16x16x32_bf16(al[i], bh[j], acc[i][j], 0, 0, 0);
            }
        __syncthreads();
    }
    int pxbase = blockIdx.x * 256 + wave * 64;
#pragma unroll
    for (int i = 0; i < 4; i++)
#pragma unroll
        for (int j = 0; j < 4; j++) {
            int col = j * 16 + l16;
            float bv = bias[col];
#pragma unroll
            for (int r = 0; r < 4; r++) {
                int prow = pxbase + i * 16 + quad * 4 + r;
                float v = fmaxf(acc[i][j][r] + bv, 0.f);
                unsigned short h = f2b(v);
                yhi[(long)prow * 64 + col] = h;
                ylo[(long)prow * 64 + col] = f2b(v - b2f(h));
            }
        }
}

// ============ fc: split-bf16 MFMA GEMM [2048,3136]x[3136,512], relu, f32 + bf16 out ============
__global__ __launch_bounds__(256) void fc_k(
    const unsigned short* __restrict__ Ahi, const unsigned short* __restrict__ Alo,
    const unsigned short* __restrict__ Bhi, const unsigned short* __restrict__ Blo,
    const float* __restrict__ bias, float* __restrict__ Cf, unsigned short* __restrict__ Cb) {
    __shared__ unsigned short Ash[64][40], Asl[64][40], Bsh[64][40], Bsl[64][40];
    int t = threadIdx.x;
    int m0 = blockIdx.x * 64, n0 = blockIdx.y * 64;
    int wave = t >> 6, lane = t & 63, l16 = lane & 15, quad = lane >> 4;
    int wm = (wave & 1) * 32, wn = (wave >> 1) * 32;
    int sr = t >> 2, sk = (t & 3) * 8;
    f32x4 acc[2][2];
#pragma unroll
    for (int i = 0; i < 2; i++)
#pragma unroll
        for (int j = 0; j < 2; j++)
#pragma unroll
            for (int r = 0; r < 4; r++) acc[i][j][r] = 0.f;
    for (int k0 = 0; k0 < 3136; k0 += 32) {
        *(bf16x8*)&Ash[sr][sk] = *(const bf16x8*)(Ahi + (long)(m0 + sr) * 3136 + k0 + sk);
        *(bf16x8*)&Asl[sr][sk] = *(const bf16x8*)(Alo + (long)(m0 + sr) * 3136 + k0 + sk);
        *(bf16x8*)&Bsh[sr][sk] = *(const bf16x8*)(Bhi + (long)(n0 + sr) * 3136 + k0 + sk);
        *(bf16x8*)&Bsl[sr][sk] = *(const bf16x8*)(Blo + (long)(n0 + sr) * 3136 + k0 + sk);
        __syncthreads();
        bf16x8 ah[2], al[2], bh[2], bl[2];
#pragma unroll
        for (int i = 0; i < 2; i++) {
            ah[i] = *(const bf16x8*)&Ash[wm + i * 16 + l16][quad * 8];
            al[i] = *(const bf16x8*)&Asl[wm + i * 16 + l16][quad * 8];
            bh[i] = *(const bf16x8*)&Bsh[wn + i * 16 + l16][quad * 8];
            bl[i] = *(const bf16x8*)&Bsl[wn + i * 16 + l16][quad * 8];
        }
#pragma unroll
        for (int i = 0; i < 2; i++)
#pragma unroll
            for (int j = 0; j < 2; j++) {
                acc[i][j] = __builtin_amdgcn_mfma_f32_16x16x32_bf16(ah[i], bh[j], acc[i][j], 0, 0, 0);
                acc[i][j] = __builtin_amdgcn_mfma_f32_16x16x32_bf16(ah[i], bl[j], acc[i][j], 0, 0, 0);
                acc[i][j] = __builtin_amdgcn_mfma_f32_16x16x32_bf16(al[i], bh[j], acc[i][j], 0, 0, 0);
            }
        __syncthreads();
    }
#pragma unroll
    for (int mt = 0; mt < 2; mt++)
#pragma unroll
        for (int nt = 0; nt < 2; nt++) {
            int col = n0 + wn + nt * 16 + l16;
            float bcol = bias[col];
#pragma unroll
            for (int r = 0; r < 4; r++) {
                int row = m0 + wm + mt * 16 + quad * 4 + r;
                float v = fmaxf(acc[mt][nt][r] + bcol, 0.f);
                Cf[row * 512 + col] = v;
                Cb[row * 512 + col] = f2b(v);
            }
        }
}

// ============ gate: logits, top-2, renormalized probs (fp32, exact) ============
__global__ __launch_bounds__(256) void gate_k(
    const float* __restrict__ f, const float* __restrict__ gw, const float* __restrict__ gb,
    int* __restrict__ topi, float* __restrict__ topp) {
    int wave = threadIdx.x >> 6, lane = threadIdx.x & 63;
    int row = blockIdx.x * 4 + wave;
    float fv[8];
#pragma unroll
    for (int j = 0; j < 8; j++) fv[j] = f[row * 512 + lane + 64 * j];
    float lg[6];
#pragma unroll
    for (int e = 0; e < 6; e++) {
        float a = 0.f;
#pragma unroll
        for (int j = 0; j < 8; j++) a += fv[j] * gw[(lane + 64 * j) * 6 + e];
#pragma unroll
        for (int off = 32; off > 0; off >>= 1) a += __shfl_xor(a, off, 64);
        lg[e] = a + gb[e];
    }
    if (lane == 0) {
        int i1 = 0;
        float v1 = lg[0];
#pragma unroll
        for (int e = 1; e < 6; e++)
            if (lg[e] > v1) { v1 = lg[e]; i1 = e; }
        int i2 = (i1 == 0) ? 1 : 0;
        float v2 = lg[i2];
#pragma unroll
        for (int e = 0; e < 6; e++)
            if (e != i1 && lg[e] > v2) { v2 = lg[e]; i2 = e; }
        float pa = 1.f / (1.f + expf(v2 - v1));
        topi[row * 2] = i1;
        topi[row * 2 + 1] = i2;
        topp[row * 2] = pa;
        topp[row * 2 + 1] = 1.f - pa;
    }
}

// ============ expert GEMM: bf16 MFMA (verified round-1 pattern) ============
__global__ __launch_bounds__(256) void moe_gemm(
    const unsigned short* __restrict__ A, long aStride,
    const unsigned short* __restrict__ Bt, const float* __restrict__ bias,
    unsigned short* __restrict__ C) {
    int e = blockIdx.z;
    const unsigned short* Ae = A + (long)e * aStride;
    const unsigned short* Be = Bt + (long)e * 262144;
    const float* be = bias + e * 512;
    unsigned short* Ce = C + (long)e * 2048 * 512;
    __shared__ unsigned short As[64 * 40];
    __shared__ unsigned short Bs[64 * 40];
    int t = threadIdx.x;
    int m0 = blockIdx.x * 64, n0 = blockIdx.y * 64;
    int wave = t >> 6, lane = t & 63;
    int l16 = lane & 15, quad = lane >> 4;
    int wm = (wave & 1) * 32, wn = (wave >> 1) * 32;
    int sm = t >> 2, sk = (t & 3) * 8;
    f32x4 acc[2][2];
#pragma unroll
    for (int i = 0; i < 2; i++)
#pragma unroll
        for (int j = 0; j < 2; j++)
#pragma unroll
            for (int r = 0; r < 4; r++) acc[i][j][r] = 0.f;
    for (int k0 = 0; k0 < 512; k0 += 32) {
        bf16x8 av = *(const bf16x8*)&Ae[(long)(m0 + sm) * 512 + k0 + sk];
        bf16x8 bv = *(const bf16x8*)&Be[(long)(n0 + sm) * 512 + k0 + sk];
        *(bf16x8*)&As[sm * 40 + sk] = av;
        *(bf16x8*)&Bs[sm * 40 + sk] = bv;
        __syncthreads();
        bf16x8 af0 = *(const bf16x8*)&As[(wm + l16) * 40 + quad * 8];
        bf16x8 af1 = *(const bf16x8*)&As[(wm + 16 + l16) * 40 + quad * 8];
        bf16x8 bf0 = *(const bf16x8*)&Bs[(wn + l16) * 40 + quad * 8];
        bf16x8 bf1 = *(const bf16x8*)&Bs[(wn + 16 + l16) * 40 + quad * 8];
        acc[0][0] = __builtin_amdgcn_mfma_f32_16x16x32_bf16(af0, bf0, acc[0][0], 0, 0, 0);
        acc[0][1] = __builtin_amdgcn_mfma_f32_16x16x32_bf16(af0, bf1, acc[0][1], 0, 0, 0);
        acc[1][0] = __builtin_amdgcn_mfma_f32_16x16x32_bf16(af1, bf0, acc[1][0], 0, 0, 0);
        acc[1][1] = __builtin_amdgcn_mfma_f32_16x16x32_bf16(af1, bf1, acc[1][1], 0, 0, 0);
        __syncthreads();
    }
#pragma unroll
    for (int mt = 0; mt < 2; mt++)
#pragma unroll
        for (int nt = 0; nt < 2; nt++) {
            int col = n0 + wn + nt * 16 + l16;
            float bcol = be[col];
#pragma unroll
            for (int r = 0; r < 4; r++) {
                int row = m0 + wm + mt * 16 + quad * 4 + r;
                float v = fmaxf(acc[mt][nt][r] + bcol, 0.f);
                Ce[(long)row * 512 + col] = f2b(v);
            }
        }
}

// ============ final expert layer (512->12) + weighted combine ============
__global__ __launch_bounds__(256) void combine_k(
    const unsigned short* __restrict__ h2, const float* __restrict__ w3,
    const float* __restrict__ b3, const int* __restrict__ topi,
    const float* __restrict__ topp, float* __restrict__ out) {
    int tid = blockIdx.x * 256 + threadIdx.x;
    if (tid >= 2048 * 12) return;
    int b = tid / 12, a = tid % 12;
    float r = 0.f;
#pragma unroll
    for (int j = 0; j < 2; j++) {
        int e = topi[b * 2 + j];
        float p = topp[b * 2 + j];
        const unsigned short* h = h2 + ((long)e * 2048 + b) * 512;
        const float* w = w3 + e * 512 * 12 + a;
        float acc = b3[e * 12 + a];
#pragma unroll 4
        for (int k = 0; k < 512; k++) acc += b2f(h[k]) * w[k * 12];
        r += p * acc;
    }
    out[tid] = r;
}

extern "C" void kernel_launch(void* const* d_in, const int* in_sizes, int n_in,
                              void* d_out, int out_size, void* d_ws, size_t ws_size,
                              hipStream_t stream) {
    const float* x   = (const float*)d_in[0];
    const float* c1w = (const float*)d_in[1];
    const float* c1b = (const float*)d_in[2];
    const float* c2w = (const float*)d_in[3];
    const float* c2b = (const float*)d_in[4];
    const float* c3w = (const float*)d_in[5];
    const float* c3b = (const float*)d_in[6];
    const float* fcw = (const float*)d_in[7];
    const float* fcb = (const float*)d_in[8];
    const float* gw  = (const float*)d_in[9];
    const float* gb  = (const float*)d_in[10];
    const float* ew1 = (const float*)d_in[11];
    const float* eb1 = (const float*)d_in[12];
    const float* ew2 = (const float*)d_in[13];
    const float* eb2 = (const float*)d_in[14];
    const float* ew3 = (const float*)d_in[15];
    const float* eb3 = (const float*)d_in[16];

    char* ws = (char*)d_ws;
    // region A: conv1 out (y1) [0, 104857600); f3 aliases it after conv2 consumes y1
    unsigned short* y1hi = (unsigned short*)(ws + 0L);          // 2048*400*32 bf16 = 52428800 B
    unsigned short* y1lo = (unsigned short*)(ws + 52428800L);   // 52428800 B
    unsigned short* f3hi = (unsigned short*)(ws + 0L);          // 2048*3136 bf16 = 12845056 B (alias, y1 dead)
    unsigned short* f3lo = (unsigned short*)(ws + 12845056L);   // 12845056 B (alias)
    // region B: conv2 out (y2) [104857600, 147324928); h1/h2 alias it after conv3
    unsigned short* y2hi = (unsigned short*)(ws + 104857600L);  // 2048*81*64 = 21233664 B
    unsigned short* y2lo = (unsigned short*)(ws + 126091264L);  // 21233664 B
    unsigned short* h1   = (unsigned short*)(ws + 104857600L);  // 6*2048*512 = 12582912 B (alias, y2 dead)
    unsigned short* h2   = (unsigned short*)(ws + 117440512L);  // 12582912 B (alias)
    float* f             = (float*)(ws + 147324928L);           // 2048*512 f32 = 4194304 B
    unsigned short* fb   = (unsigned short*)(ws + 151519232L);  // 2097152 B
    int*   topi          = (int*)(ws + 153616384L);             // 16384 B
    float* topp          = (float*)(ws + 153632768L);           // 16384 B
    float* w1r           = (float*)(ws + 153649152L);           // 32768 B
    unsigned short* w2h  = (unsigned short*)(ws + 153681920L);  // 65536 B
    unsigned short* w2l  = (unsigned short*)(ws + 153747456L);  // 65536 B
    unsigned short* w3h  = (unsigned short*)(ws + 153812992L);  // 73728 B
    unsigned short* w3l  = (unsigned short*)(ws + 153886720L);  // 73728 B
    unsigned short* fcwh = (unsigned short*)(ws + 153960448L);  // 3211264 B
    unsigned short* fcwl = (unsigned short*)(ws + 157171712L);  // 3211264 B
    unsigned short* ew1t = (unsigned short*)(ws + 160382976L);  // 3145728 B
    unsigned short* ew2t = (unsigned short*)(ws + 163528704L);  // 3145728 B  (end 166674432)
    float* out = (float*)d_out;

    hipLaunchKernelGGL(prep_w, dim3(304), dim3(256), 0, stream, c1w, c2w, c3w, w1r, w2h, w2l, w3h, w3l);
    hipLaunchKernelGGL(prep_fcw, dim3(49, 8), dim3(256), 0, stream, fcw, fcwh, fcwl);
    hipLaunchKernelGGL(prep_ewT, dim3(16, 16, 12), dim3(32, 8), 0, stream, ew1, ew2, ew1t, ew2t);
    hipLaunchKernelGGL(conv1_k, dim3(3200), dim3(256), 0, stream, x, w1r, c1b, y1hi, y1lo);
    hipLaunchKernelGGL((convm_k<32, 20, 20, 9, 9, 2, 4, 4>), dim3(648), dim3(256), 0, stream,
                       y1hi, y1lo, w2h, w2l, c2b, y2hi, y2lo);
    hipLaunchKernelGGL((convm_k<64, 9, 9, 7, 7, 1, 3, 3>), dim3(392), dim3(256), 0, stream,
                       y2hi, y2lo, w3h, w3l, c3b, f3hi, f3lo);
    hipLaunchKernelGGL(fc_k, dim3(32, 8), dim3(256), 0, stream, f3hi, f3lo, fcwh, fcwl, fcb, f, fb);
    hipLaunchKernelGGL(gate_k, dim3(512), dim3(256), 0, stream, f, gw, gb, topi, topp);
    hipLaunchKernelGGL(moe_gemm, dim3(32, 8, 6), dim3(256), 0, stream, fb, 0L, ew1t, eb1, h1);
    hipLaunchKernelGGL(moe_gemm, dim3(32, 8, 6), dim3(256), 0, stream, h1, 1048576L, ew2t, eb2, h2);
    hipLaunchKernelGGL(combine_k, dim3(96), dim3(256), 0, stream, h2, ew3, eb3, topi, topp, out);
}

// Round 3
// 715.126 us; speedup vs baseline: 1.9741x; 1.1920x over previous
//
#include <hip/hip_runtime.h>
#include <hip/hip_bf16.h>
#include <math.h>

typedef __attribute__((ext_vector_type(8))) short bf16x8;
typedef __attribute__((ext_vector_type(4))) float f32x4;

__device__ __forceinline__ float b2f(unsigned short u) {
    unsigned int v = ((unsigned int)u) << 16;
    return __uint_as_float(v);
}
__device__ __forceinline__ unsigned short f2b(float f) {
    __hip_bfloat16 h = __float2bfloat16(f);
    return *reinterpret_cast<unsigned short*>(&h);
}
// truncation split: hi = top 16 bits, lo = RNE(v - hi). residual ~2^-17 |v|
__device__ __forceinline__ void split_trunc(float v, short& h, short& l) {
    unsigned int ui = __float_as_uint(v);
    h = (short)(ui >> 16);
    float hf = __uint_as_float(ui & 0xffff0000u);
    l = (short)f2b(v - hf);
}

// ============ prep: conv + w3 weights ============
__global__ __launch_bounds__(256) void prep_w(
    const float* __restrict__ w1, const float* __restrict__ w2, const float* __restrict__ w3,
    const float* __restrict__ ew3,
    unsigned short* __restrict__ wb1h, unsigned short* __restrict__ wb1l,
    unsigned short* __restrict__ w2h, unsigned short* __restrict__ w2l,
    unsigned short* __restrict__ w3h, unsigned short* __restrict__ w3l,
    float* __restrict__ w3t) {
    int tid = blockIdx.x * 256 + threadIdx.x;
    if (tid < 8192) {
        int k = tid >> 8, r = tid & 255;
        int c = r >> 6, ky = (r >> 3) & 7, kx = r & 7;
        float v = w1[tid];
        unsigned short h = f2b(v);
        int d = ((ky * 2 + (k >> 4)) * 16 + (k & 15)) * 32 + c * 8 + kx;
        wb1h[d] = h;
        wb1l[d] = f2b(v - b2f(h));
    } else if (tid < 8192 + 32768) {
        int i = tid - 8192;
        int n = i >> 9, r = i & 511;
        int c = r >> 4, ky = (r >> 2) & 3, kx = r & 3;
        float v = w2[i];
        unsigned short h = f2b(v);
        int d = ((ky * 4 + kx) * 64 + n) * 32 + c;
        w2h[d] = h;
        w2l[d] = f2b(v - b2f(h));
    } else if (tid < 8192 + 32768 + 36864) {
        int i = tid - 40960;
        int n = i / 576, r = i - n * 576;
        int c = r / 9, s = r - c * 9;
        int ky = s / 3, kx = s - ky * 3;
        float v = w3[i];
        unsigned short h = f2b(v);
        int d = (((ky * 3 + kx) * 2 + (c >> 5)) * 64 + n) * 32 + (c & 31);
        w3h[d] = h;
        w3l[d] = f2b(v - b2f(h));
    } else if (tid < 77824 + 36864) {
        int i = tid - 77824;
        int e = i / 6144, rem = i - e * 6144;
        int a = rem >> 9, k = rem & 511;
        w3t[i] = ew3[e * 6144 + k * 12 + a];
    }
}

// ============ prep: fc weights ============
__global__ __launch_bounds__(256) void prep_fcw(
    const float* __restrict__ fw, unsigned short* __restrict__ h, unsigned short* __restrict__ l) {
    __shared__ float tile[64][65];
    int k0 = blockIdx.x * 64;
    int n0 = blockIdx.y * 64;
    int tx = threadIdx.x & 63, ty = threadIdx.x >> 6;
#pragma unroll
    for (int j = 0; j < 16; j++) {
        int kk = ty + j * 4;
        int kp = k0 + kk;
        int p = kp >> 6, c = kp & 63;
        tile[kk][tx] = fw[(c * 49 + p) * 512 + n0 + tx];
    }
    __syncthreads();
#pragma unroll
    for (int j = 0; j < 16; j++) {
        int r = ty + j * 4;
        float v = tile[tx][r];
        unsigned short hh = f2b(v);
        long d = (long)(n0 + r) * 3136 + k0 + tx;
        h[d] = hh;
        l[d] = f2b(v - b2f(hh));
    }
}

// ============ prep: expert weights [e][d][h] -> bf16 [e][h][d] ============
__global__ __launch_bounds__(256) void prep_ewT(
    const float* __restrict__ ew1, const float* __restrict__ ew2,
    unsigned short* __restrict__ t1, unsigned short* __restrict__ t2) {
    __shared__ float tile[32][33];
    int z = blockIdx.z;
    int e = z % 6;
    const float* src = (z < 6) ? (ew1 + e * 262144) : (ew2 + e * 262144);
    unsigned short* dst = (z < 6) ? (t1 + e * 262144) : (t2 + e * 262144);
    int d0 = blockIdx.y * 32;
    int h0 = blockIdx.x * 32;
    int tx = threadIdx.x, ty = threadIdx.y;
#pragma unroll
    for (int j = 0; j < 4; j++)
        tile[ty + j * 8][tx] = src[(d0 + ty + j * 8) * 512 + h0 + tx];
    __syncthreads();
#pragma unroll
    for (int j = 0; j < 4; j++)
        dst[(h0 + ty + j * 8) * 512 + (d0 + tx)] = f2b(tile[tx][ty + j * 8]);
}

// ============ conv1: direct MFMA from global, split-bf16, no im2col ============
__global__ __launch_bounds__(256) void conv1_k(
    const float* __restrict__ x, const unsigned short* __restrict__ wbh,
    const unsigned short* __restrict__ wbl, const float* __restrict__ b1,
    unsigned short* __restrict__ yhi, unsigned short* __restrict__ ylo) {
    int t = threadIdx.x;
    int wave = t >> 6, lane = t & 63, l16 = lane & 15, quad = lane >> 4;
    int px0 = blockIdx.x * 256 + wave * 64;
    const float* abase[4];
#pragma unroll
    for (int i = 0; i < 4; i++) {
        int px = px0 + i * 16 + l16;
        int n = px / 400;
        int rem = px - n * 400;
        int oy = rem / 20;
        int ox = rem - oy * 20;
        abase[i] = x + (long)n * 28224 + quad * 7056 + oy * 4 * 84 + ox * 4;
    }
    f32x4 acc[4][2];
#pragma unroll
    for (int i = 0; i < 4; i++)
#pragma unroll
        for (int j = 0; j < 2; j++)
#pragma unroll
            for (int r = 0; r < 4; r++) acc[i][j][r] = 0.f;
#pragma unroll
    for (int ky = 0; ky < 8; ky++) {
        bf16x8 ah[4], al[4];
#pragma unroll
        for (int i = 0; i < 4; i++) {
            const float* p = abase[i] + ky * 84;
            float4 v0 = *(const float4*)p;
            float4 v1 = *(const float4*)(p + 4);
            float v[8] = {v0.x, v0.y, v0.z, v0.w, v1.x, v1.y, v1.z, v1.w};
#pragma unroll
            for (int j = 0; j < 8; j++) {
                short hh, ll;
                split_trunc(v[j], hh, ll);
                ah[i][j] = hh;
                al[i][j] = ll;
            }
        }
        int wo = (ky * 2 * 16 + l16) * 32 + quad * 8;
        bf16x8 bh0 = *(const bf16x8*)(wbh + wo);
        bf16x8 bh1 = *(const bf16x8*)(wbh + wo + 512);
        bf16x8 bl0 = *(const bf16x8*)(wbl + wo);
        bf16x8 bl1 = *(const bf16x8*)(wbl + wo + 512);
#pragma unroll
        for (int i = 0; i < 4; i++) {
            acc[i][0] = __builtin_amdgcn_mfma_f32_16x16x32_bf16(ah[i], bh0, acc[i][0], 0, 0, 0);
            acc[i][0] = __builtin_amdgcn_mfma_f32_16x16x32_bf16(al[i], bh0, acc[i][0], 0, 0, 0);
            acc[i][0] = __builtin_amdgcn_mfma_f32_16x16x32_bf16(ah[i], bl0, acc[i][0], 0, 0, 0);
            acc[i][1] = __builtin_amdgcn_mfma_f32_16x16x32_bf16(ah[i], bh1, acc[i][1], 0, 0, 0);
            acc[i][1] = __builtin_amdgcn_mfma_f32_16x16x32_bf16(al[i], bh1, acc[i][1], 0, 0, 0);
            acc[i][1] = __builtin_amdgcn_mfma_f32_16x16x32_bf16(ah[i], bl1, acc[i][1], 0, 0, 0);
        }
    }
    float bias0 = b1[l16], bias1 = b1[16 + l16];
#pragma unroll
    for (int i = 0; i < 4; i++) {
#pragma unroll
        for (int r = 0; r < 4; r++) {
            long px = px0 + i * 16 + quad * 4 + r;
            long o = px * 32;
            float v0 = fmaxf(acc[i][0][r] + bias0, 0.f);
            float v1 = fmaxf(acc[i][1][r] + bias1, 0.f);
            short h0, l0, h1, l1;
            split_trunc(v0, h0, l0);
            split_trunc(v1, h1, l1);
            yhi[o + l16] = (unsigned short)h0;
            ylo[o + l16] = (unsigned short)l0;
            yhi[o + 16 + l16] = (unsigned short)h1;
            ylo[o + 16 + l16] = (unsigned short)l1;
        }
    }
}

// ============ conv as implicit-GEMM MFMA, split-bf16 ============
template <int C, int IH, int IW, int OH, int OW, int S, int KH, int KW>
__global__ __launch_bounds__(256) void convm_k(
    const unsigned short* __restrict__ xhi, const unsigned short* __restrict__ xlo,
    const unsigned short* __restrict__ whi, const unsigned short* __restrict__ wlo,
    const float* __restrict__ bias,
    unsigned short* __restrict__ yhi, unsigned short* __restrict__ ylo) {
    constexpr int CH = C / 32;
    constexpr int NCHUNK = KH * KW * CH;
    __shared__ unsigned short Ah[256][40], Al[256][40], Bh[64][40], Bl[64][40];
    int t = threadIdx.x;
    int px = blockIdx.x * 256 + t;
    int n = px / (OH * OW);
    int rem = px - n * (OH * OW);
    int oy = rem / OW;
    int ox = rem - oy * OW;
    const long xoff = (((long)n * IH + oy * S) * IW + ox * S) * C;
    int wave = t >> 6, lane = t & 63, l16 = lane & 15, quad = lane >> 4;
    int br = t >> 2, bc = (t & 3) * 8;
    f32x4 acc[4][4];
#pragma unroll
    for (int i = 0; i < 4; i++)
#pragma unroll
        for (int j = 0; j < 4; j++)
#pragma unroll
            for (int r = 0; r < 4; r++) acc[i][j][r] = 0.f;
    for (int ck = 0; ck < NCHUNK; ck++) {
        int kyx = ck / CH;
        int ch = ck - kyx * CH;
        int ky = kyx / KW, kx = kyx - ky * KW;
        long a_src = xoff + ((ky * IW + kx) * C + ch * 32);
#pragma unroll
        for (int j = 0; j < 4; j++) {
            *(bf16x8*)&Ah[t][j * 8] = *(const bf16x8*)(xhi + a_src + j * 8);
            *(bf16x8*)&Al[t][j * 8] = *(const bf16x8*)(xlo + a_src + j * 8);
        }
        long b_src = (long)ck * 2048 + br * 32 + bc;
        *(bf16x8*)&Bh[br][bc] = *(const bf16x8*)(whi + b_src);
        *(bf16x8*)&Bl[br][bc] = *(const bf16x8*)(wlo + b_src);
        __syncthreads();
        bf16x8 ah[4], al[4], bh[4], bl[4];
#pragma unroll
        for (int i = 0; i < 4; i++) {
            ah[i] = *(const bf16x8*)&Ah[wave * 64 + i * 16 + l16][quad * 8];
            al[i] = *(const bf16x8*)&Al[wave * 64 + i * 16 + l16][quad * 8];
            bh[i] = *(const bf16x8*)&Bh[i * 16 + l16][quad * 8];
            bl[i] = *(const bf16x8*)&Bl[i * 16 + l16][quad * 8];
        }
#pragma unroll
        for (int i = 0; i < 4; i++)
#pragma unroll
            for (int j = 0; j < 4; j++) {
                acc[i][j] = __builtin_amdgcn_mfma_f32_16x16x32_bf16(ah[i], bh[j], acc[i][j], 0, 0, 0);
                acc[i][j] = __builtin_amdgcn_mfma_f32_16x16x32_bf16(ah[i], bl[j], acc[i][j], 0, 0, 0);
                acc[i][j] = __builtin_amdgcn_mfma_f32_16x16x32_bf16(al[i], bh[j], acc[i][j], 0, 0, 0);
            }
        __syncthreads();
    }
    int pxbase = blockIdx.x * 256 + wave * 64;
#pragma unroll
    for (int i = 0; i < 4; i++)
#pragma unroll
        for (int j = 0; j < 4; j++) {
            int col = j * 16 + l16;
            float bv = bias[col];
#pragma unroll
            for (int r = 0; r < 4; r++) {
                int prow = pxbase + i * 16 + quad * 4 + r;
                float v = fmaxf(acc[i][j][r] + bv, 0.f);
                unsigned short h = f2b(v);
                yhi[(long)prow * 64 + col] = h;
                ylo[(long)prow * 64 + col] = f2b(v - b2f(h));
            }
        }
}

// ============ fc: split-bf16 MFMA GEMM, K-split x2, writes fp32 partials ============
__global__ __launch_bounds__(256) void fc_k(
    const unsigned short* __restrict__ Ahi, const unsigned short* __restrict__ Alo,
    const unsigned short* __restrict__ Bhi, const unsigned short* __restrict__ Blo,
    float* __restrict__ Cp) {
    __shared__ unsigned short Ash[64][40], Asl[64][40], Bsh[64][40], Bsl[64][40];
    int t = threadIdx.x;
    int m0 = blockIdx.x * 64, n0 = blockIdx.y * 64;
    int z = blockIdx.z;
    int kBase = z * 1568;
    int wave = t >> 6, lane = t & 63, l16 = lane & 15, quad = lane >> 4;
    int wm = (wave & 1) * 32, wn = (wave >> 1) * 32;
    int sr = t >> 2, sk = (t & 3) * 8;
    f32x4 acc[2][2];
#pragma unroll
    for (int i = 0; i < 2; i++)
#pragma unroll
        for (int j = 0; j < 2; j++)
#pragma unroll
            for (int r = 0; r < 4; r++) acc[i][j][r] = 0.f;
    for (int k0 = kBase; k0 < kBase + 1568; k0 += 32) {
        *(bf16x8*)&Ash[sr][sk] = *(const bf16x8*)(Ahi + (long)(m0 + sr) * 3136 + k0 + sk);
        *(bf16x8*)&Asl[sr][sk] = *(const bf16x8*)(Alo + (long)(m0 + sr) * 3136 + k0 + sk);
        *(bf16x8*)&Bsh[sr][sk] = *(const bf16x8*)(Bhi + (long)(n0 + sr) * 3136 + k0 + sk);
        *(bf16x8*)&Bsl[sr][sk] = *(const bf16x8*)(Blo + (long)(n0 + sr) * 3136 + k0 + sk);
        __syncthreads();
        bf16x8 ah[2], al[2], bh[2], bl[2];
#pragma unroll
        for (int i = 0; i < 2; i++) {
            ah[i] = *(const bf16x8*)&Ash[wm + i * 16 + l16][quad * 8];
            al[i] = *(const bf16x8*)&Asl[wm + i * 16 + l16][quad * 8];
            bh[i] = *(const bf16x8*)&Bsh[wn + i * 16 + l16][quad * 8];
            bl[i] = *(const bf16x8*)&Bsl[wn + i * 16 + l16][quad * 8];
        }
#pragma unroll
        for (int i = 0; i < 2; i++)
#pragma unroll
            for (int j = 0; j < 2; j++) {
                acc[i][j] = __builtin_amdgcn_mfma_f32_16x16x32_bf16(ah[i], bh[j], acc[i][j], 0, 0, 0);
                acc[i][j] = __builtin_amdgcn_mfma_f32_16x16x32_bf16(ah[i], bl[j], acc[i][j], 0, 0, 0);
                acc[i][j] = __builtin_amdgcn_mfma_f32_16x16x32_bf16(al[i], bh[j], acc[i][j], 0, 0, 0);
            }
        __syncthreads();
    }
    float* Cz = Cp + (long)z * 1048576;
#pragma unroll
    for (int mt = 0; mt < 2; mt++)
#pragma unroll
        for (int nt = 0; nt < 2; nt++) {
            int col = n0 + wn + nt * 16 + l16;
#pragma unroll
            for (int r = 0; r < 4; r++) {
                int row = m0 + wm + mt * 16 + quad * 4 + r;
                Cz[row * 512 + col] = acc[mt][nt][r];
            }
        }
}

// ============ fc finalize ============
__global__ __launch_bounds__(256) void fc_fin(
    const float* __restrict__ Cp, const float* __restrict__ bias,
    float* __restrict__ f, unsigned short* __restrict__ fb) {
    int tid = blockIdx.x * 256 + threadIdx.x;
    int col = tid & 511;
    float v = Cp[tid] + Cp[tid + 1048576] + bias[col];
    v = fmaxf(v, 0.f);
    f[tid] = v;
    fb[tid] = f2b(v);
}

// ============ gate ============
__global__ __launch_bounds__(256) void gate_k(
    const float* __restrict__ f, const float* __restrict__ gw, const float* __restrict__ gb,
    int* __restrict__ topi, float* __restrict__ topp) {
    int wave = threadIdx.x >> 6, lane = threadIdx.x & 63;
    int row = blockIdx.x * 4 + wave;
    float fv[8];
#pragma unroll
    for (int j = 0; j < 8; j++) fv[j] = f[row * 512 + lane + 64 * j];
    float lg[6];
#pragma unroll
    for (int e = 0; e < 6; e++) {
        float a = 0.f;
#pragma unroll
        for (int j = 0; j < 8; j++) a += fv[j] * gw[(lane + 64 * j) * 6 + e];
#pragma unroll
        for (int off = 32; off > 0; off >>= 1) a += __shfl_xor(a, off, 64);
        lg[e] = a + gb[e];
    }
    if (lane == 0) {
        int i1 = 0;
        float v1 = lg[0];
#pragma unroll
        for (int e = 1; e < 6; e++)
            if (lg[e] > v1) { v1 = lg[e]; i1 = e; }
        int i2 = (i1 == 0) ? 1 : 0;
        float v2 = lg[i2];
#pragma unroll
        for (int e = 0; e < 6; e++)
            if (e != i1 && lg[e] > v2) { v2 = lg[e]; i2 = e; }
        float pa = 1.f / (1.f + expf(v2 - v1));
        topi[row * 2] = i1;
        topi[row * 2 + 1] = i2;
        topp[row * 2] = pa;
        topp[row * 2 + 1] = 1.f - pa;
    }
}

// ============ expert GEMM ============
__global__ __launch_bounds__(256) void moe_gemm(
    const unsigned short* __restrict__ A, long aStride,
    const unsigned short* __restrict__ Bt, const float* __restrict__ bias,
    unsigned short* __restrict__ C) {
    int e = blockIdx.z;
    const unsigned short* Ae = A + (long)e * aStride;
    const unsigned short* Be = Bt + (long)e * 262144;
    const float* be = bias + e * 512;
    unsigned short* Ce = C + (long)e * 2048 * 512;
    __shared__ unsigned short As[64 * 40];
    __shared__ unsigned short Bs[64 * 40];
    int t = threadIdx.x;
    int m0 = blockIdx.x * 64, n0 = blockIdx.y * 64;
    int wave = t >> 6, lane = t & 63;
    int l16 = lane & 15, quad = lane >> 4;
    int wm = (wave & 1) * 32, wn = (wave >> 1) * 32;
    int sm = t >> 2, sk = (t & 3) * 8;
    f32x4 acc[2][2];
#pragma unroll
    for (int i = 0; i < 2; i++)
#pragma unroll
        for (int j = 0; j < 2; j++)
#pragma unroll
            for (int r = 0; r < 4; r++) acc[i][j][r] = 0.f;
    for (int k0 = 0; k0 < 512; k0 += 32) {
        bf16x8 av = *(const bf16x8*)&Ae[(long)(m0 + sm) * 512 + k0 + sk];
        bf16x8 bv = *(const bf16x8*)&Be[(long)(n0 + sm) * 512 + k0 + sk];
        *(bf16x8*)&As[sm * 40 + sk] = av;
        *(bf16x8*)&Bs[sm * 40 + sk] = bv;
        __syncthreads();
        bf16x8 af0 = *(const bf16x8*)&As[(wm + l16) * 40 + quad * 8];
        bf16x8 af1 = *(const bf16x8*)&As[(wm + 16 + l16) * 40 + quad * 8];
        bf16x8 bf0 = *(const bf16x8*)&Bs[(wn + l16) * 40 + quad * 8];
        bf16x8 bf1 = *(const bf16x8*)&Bs[(wn + 16 + l16) * 40 + quad * 8];
        acc[0][0] = __builtin_amdgcn_mfma_f32_16x16x32_bf16(af0, bf0, acc[0][0], 0, 0, 0);
        acc[0][1] = __builtin_amdgcn_mfma_f32_16x16x32_bf16(af0, bf1, acc[0][1], 0, 0, 0);
        acc[1][0] = __builtin_amdgcn_mfma_f32_16x16x32_bf16(af1, bf0, acc[1][0], 0, 0, 0);
        acc[1][1] = __builtin_amdgcn_mfma_f32_16x16x32_bf16(af1, bf1, acc[1][1], 0, 0, 0);
        __syncthreads();
    }
#pragma unroll
    for (int mt = 0; mt < 2; mt++)
#pragma unroll
        for (int nt = 0; nt < 2; nt++) {
            int col = n0 + wn + nt * 16 + l16;
            float bcol = be[col];
#pragma unroll
            for (int r = 0; r < 4; r++) {
                int row = m0 + wm + mt * 16 + quad * 4 + r;
                float v = fmaxf(acc[mt][nt][r] + bcol, 0.f);
                Ce[(long)row * 512 + col] = f2b(v);
            }
        }
}

// ============ combine: wave per row, coalesced, shuffle-reduce ============
__global__ __launch_bounds__(256) void combine_k(
    const unsigned short* __restrict__ h2, const float* __restrict__ w3t,
    const float* __restrict__ b3, const int* __restrict__ topi,
    const float* __restrict__ topp, float* __restrict__ out) {
    int b = blockIdx.x * 4 + (threadIdx.x >> 6);
    int lane = threadIdx.x & 63;
    int e0 = topi[b * 2], e1 = topi[b * 2 + 1];
    float p0 = topp[b * 2], p1 = topp[b * 2 + 1];
    float r[12];
#pragma unroll
    for (int a = 0; a < 12; a++) r[a] = 0.f;
#pragma unroll
    for (int j = 0; j < 2; j++) {
        int e = j ? e1 : e0;
        float p = j ? p1 : p0;
        const unsigned short* hp = h2 + ((long)e * 2048 + b) * 512 + lane * 8;
        bf16x8 hv = *(const bf16x8*)hp;
        float hf[8];
#pragma unroll
        for (int q = 0; q < 8; q++) hf[q] = b2f((unsigned short)hv[q]);
        const float* wb = w3t + e * 6144 + lane * 8;
#pragma unroll
        for (int a = 0; a < 12; a++) {
            float4 w0 = *(const float4*)(wb + a * 512);
            float4 w1 = *(const float4*)(wb + a * 512 + 4);
            float acc = hf[0] * w0.x + hf[1] * w0.y + hf[2] * w0.z + hf[3] * w0.w +
                        hf[4] * w1.x + hf[5] * w1.y + hf[6] * w1.z + hf[7] * w1.w;
            r[a] += p * acc;
        }
    }
#pragma unroll
    for (int a = 0; a < 12; a++)
#pragma unroll
        for (int off = 32; off > 0; off >>= 1) r[a] += __shfl_xor(r[a], off, 64);
    float v = 0.f;
#pragma unroll
    for (int a = 0; a < 12; a++)
        if (lane == a) v = r[a];
    if (lane < 12)
        out[b * 12 + lane] = v + p0 * b3[e0 * 12 + lane] + p1 * b3[e1 * 12 + lane];
}

extern "C" void kernel_launch(void* const* d_in, const int* in_sizes, int n_in,
                              void* d_out, int out_size, void* d_ws, size_t ws_size,
                              hipStream_t stream) {
    const float* x   = (const float*)d_in[0];
    const float* c1w = (const float*)d_in[1];
    const float* c1b = (const float*)d_in[2];
    const float* c2w = (const float*)d_in[3];
    const float* c2b = (const float*)d_in[4];
    const float* c3w = (const float*)d_in[5];
    const float* c3b = (const float*)d_in[6];
    const float* fcw = (const float*)d_in[7];
    const float* fcb = (const float*)d_in[8];
    const float* gw  = (const float*)d_in[9];
    const float* gb  = (const float*)d_in[10];
    const float* ew1 = (const float*)d_in[11];
    const float* eb1 = (const float*)d_in[12];
    const float* ew2 = (const float*)d_in[13];
    const float* eb2 = (const float*)d_in[14];
    const float* ew3 = (const float*)d_in[15];
    const float* eb3 = (const float*)d_in[16];

    char* ws = (char*)d_ws;
    unsigned short* y1hi = (unsigned short*)(ws + 0L);
    unsigned short* y1lo = (unsigned short*)(ws + 52428800L);
    unsigned short* f3hi = (unsigned short*)(ws + 0L);
    unsigned short* f3lo = (unsigned short*)(ws + 12845056L);
    unsigned short* y2hi = (unsigned short*)(ws + 104857600L);
    unsigned short* y2lo = (unsigned short*)(ws + 126091264L);
    unsigned short* h1   = (unsigned short*)(ws + 104857600L);
    unsigned short* h2   = (unsigned short*)(ws + 117440512L);
    float* f             = (float*)(ws + 147324928L);
    unsigned short* fb   = (unsigned short*)(ws + 151519232L);
    int*   topi          = (int*)(ws + 153616384L);
    float* topp          = (float*)(ws + 153632768L);
    unsigned short* w2h  = (unsigned short*)(ws + 153681920L);
    unsigned short* w2l  = (unsigned short*)(ws + 153747456L);
    unsigned short* w3h  = (unsigned short*)(ws + 153812992L);
    unsigned short* w3l  = (unsigned short*)(ws + 153886720L);
    unsigned short* fcwh = (unsigned short*)(ws + 153960448L);
    unsigned short* fcwl = (unsigned short*)(ws + 157171712L);
    unsigned short* ew1t = (unsigned short*)(ws + 160382976L);
    unsigned short* ew2t = (unsigned short*)(ws + 163528704L);
    float* w3t           = (float*)(ws + 166674432L);
    float* Cp            = (float*)(ws + 166821888L);
    unsigned short* wb1h = (unsigned short*)(ws + 175210496L);
    unsigned short* wb1l = (unsigned short*)(ws + 175226880L);
    float* out = (float*)d_out;

    hipLaunchKernelGGL(prep_w, dim3(448), dim3(256), 0, stream, c1w, c2w, c3w, ew3,
                       wb1h, wb1l, w2h, w2l, w3h, w3l, w3t);
    hipLaunchKernelGGL(prep_fcw, dim3(49, 8), dim3(256), 0, stream, fcw, fcwh, fcwl);
    hipLaunchKernelGGL(prep_ewT, dim3(16, 16, 12), dim3(32, 8), 0, stream, ew1, ew2, ew1t, ew2t);
    hipLaunchKernelGGL(conv1_k, dim3(3200), dim3(256), 0, stream, x, wb1h, wb1l, c1b, y1hi, y1lo);
    hipLaunchKernelGGL((convm_k<32, 20, 20, 9, 9, 2, 4, 4>), dim3(648), dim3(256), 0, stream,
                       y1hi, y1lo, w2h, w2l, c2b, y2hi, y2lo);
    hipLaunchKernelGGL((convm_k<64, 9, 9, 7, 7, 1, 3, 3>), dim3(392), dim3(256), 0, stream,
                       y2hi, y2lo, w3h, w3l, c3b, f3hi, f3lo);
    hipLaunchKernelGGL(fc_k, dim3(32, 8, 2), dim3(256), 0, stream, f3hi, f3lo, fcwh, fcwl, Cp);
    hipLaunchKernelGGL(fc_fin, dim3(4096), dim3(256), 0, stream, Cp, fcb, f, fb);
    hipLaunchKernelGGL(gate_k, dim3(512), dim3(256), 0, stream, f, gw, gb, topi, topp);
    hipLaunchKernelGGL(moe_gemm, dim3(32, 8, 6), dim3(256), 0, stream, fb, 0L, ew1t, eb1, h1);
    hipLaunchKernelGGL(moe_gemm, dim3(32, 8, 6), dim3(256), 0, stream, h1, 1048576L, ew2t, eb2, h2);
    hipLaunchKernelGGL(combine_k, dim3(512), dim3(256), 0, stream, h2, w3t, eb3, topi, topp, out);
}

// Round 4
// 712.032 us; speedup vs baseline: 1.9827x; 1.0043x over previous
//
#include <hip/hip_runtime.h>
#include <hip/hip_bf16.h>
#include <math.h>

typedef __attribute__((ext_vector_type(8))) short bf16x8;
typedef __attribute__((ext_vector_type(4))) float f32x4;

__device__ __forceinline__ float b2f(unsigned short u) {
    unsigned int v = ((unsigned int)u) << 16;
    return __uint_as_float(v);
}
__device__ __forceinline__ unsigned short f2b(float f) {
    __hip_bfloat16 h = __float2bfloat16(f);
    return *reinterpret_cast<unsigned short*>(&h);
}
// truncation split: hi = top 16 bits, lo = RNE(v - hi). residual ~2^-17 |v|
__device__ __forceinline__ void split_trunc(float v, short& h, short& l) {
    unsigned int ui = __float_as_uint(v);
    h = (short)(ui >> 16);
    float hf = __uint_as_float(ui & 0xffff0000u);
    l = (short)f2b(v - hf);
}

// ============ prep: conv + w3 weights ============
__global__ __launch_bounds__(256) void prep_w(
    const float* __restrict__ w1, const float* __restrict__ w2, const float* __restrict__ w3,
    const float* __restrict__ ew3,
    unsigned short* __restrict__ wb1h, unsigned short* __restrict__ wb1l,
    unsigned short* __restrict__ w2h, unsigned short* __restrict__ w2l,
    unsigned short* __restrict__ w3h, unsigned short* __restrict__ w3l,
    float* __restrict__ w3t) {
    int tid = blockIdx.x * 256 + threadIdx.x;
    if (tid < 8192) {
        int k = tid >> 8, r = tid & 255;
        int c = r >> 6, ky = (r >> 3) & 7, kx = r & 7;
        float v = w1[tid];
        unsigned short h = f2b(v);
        int d = ((ky * 2 + (k >> 4)) * 16 + (k & 15)) * 32 + c * 8 + kx;
        wb1h[d] = h;
        wb1l[d] = f2b(v - b2f(h));
    } else if (tid < 8192 + 32768) {
        int i = tid - 8192;
        int n = i >> 9, r = i & 511;
        int c = r >> 4, ky = (r >> 2) & 3, kx = r & 3;
        float v = w2[i];
        unsigned short h = f2b(v);
        int d = ((ky * 4 + kx) * 64 + n) * 32 + c;
        w2h[d] = h;
        w2l[d] = f2b(v - b2f(h));
    } else if (tid < 8192 + 32768 + 36864) {
        int i = tid - 40960;
        int n = i / 576, r = i - n * 576;
        int c = r / 9, s = r - c * 9;
        int ky = s / 3, kx = s - ky * 3;
        float v = w3[i];
        unsigned short h = f2b(v);
        int d = (((ky * 3 + kx) * 2 + (c >> 5)) * 64 + n) * 32 + (c & 31);
        w3h[d] = h;
        w3l[d] = f2b(v - b2f(h));
    } else if (tid < 77824 + 36864) {
        int i = tid - 77824;
        int e = i / 6144, rem = i - e * 6144;
        int a = rem >> 9, k = rem & 511;
        w3t[i] = ew3[e * 6144 + k * 12 + a];
    }
}

// ============ prep: fc weights: fc_w[(c*49+p)*512+n] -> fcw[n][(p*64+c)] hi/lo ============
__global__ __launch_bounds__(256) void prep_fcw(
    const float* __restrict__ fw, unsigned short* __restrict__ h, unsigned short* __restrict__ l) {
    __shared__ float tile[64][65];
    int k0 = blockIdx.x * 64;
    int n0 = blockIdx.y * 64;
    int tx = threadIdx.x & 63, ty = threadIdx.x >> 6;
#pragma unroll
    for (int j = 0; j < 16; j++) {
        int kk = ty + j * 4;
        int kp = k0 + kk;
        int p = kp >> 6, c = kp & 63;
        tile[kk][tx] = fw[(c * 49 + p) * 512 + n0 + tx];
    }
    __syncthreads();
#pragma unroll
    for (int j = 0; j < 16; j++) {
        int r = ty + j * 4;
        float v = tile[tx][r];
        unsigned short hh = f2b(v);
        long d = (long)(n0 + r) * 3136 + k0 + tx;
        h[d] = hh;
        l[d] = f2b(v - b2f(hh));
    }
}

// ============ prep: expert weights [e][d][h] -> bf16 [e][h][d] ============
__global__ __launch_bounds__(256) void prep_ewT(
    const float* __restrict__ ew1, const float* __restrict__ ew2,
    unsigned short* __restrict__ t1, unsigned short* __restrict__ t2) {
    __shared__ float tile[32][33];
    int z = blockIdx.z;
    int e = z % 6;
    const float* src = (z < 6) ? (ew1 + e * 262144) : (ew2 + e * 262144);
    unsigned short* dst = (z < 6) ? (t1 + e * 262144) : (t2 + e * 262144);
    int d0 = blockIdx.y * 32;
    int h0 = blockIdx.x * 32;
    int tx = threadIdx.x, ty = threadIdx.y;
#pragma unroll
    for (int j = 0; j < 4; j++)
        tile[ty + j * 8][tx] = src[(d0 + ty + j * 8) * 512 + h0 + tx];
    __syncthreads();
#pragma unroll
    for (int j = 0; j < 4; j++)
        dst[(h0 + ty + j * 8) * 512 + (d0 + tx)] = f2b(tile[tx][ty + j * 8]);
}

// ============ conv1: direct MFMA, explicit ky+1 register prefetch ============
__global__ __launch_bounds__(256, 3) void conv1_k(
    const float* __restrict__ x, const unsigned short* __restrict__ wbh,
    const unsigned short* __restrict__ wbl, const float* __restrict__ b1,
    unsigned short* __restrict__ yhi, unsigned short* __restrict__ ylo) {
    int t = threadIdx.x;
    int wave = t >> 6, lane = t & 63, l16 = lane & 15, quad = lane >> 4;
    int px0 = blockIdx.x * 256 + wave * 64;
    const float* abase[4];
#pragma unroll
    for (int i = 0; i < 4; i++) {
        int px = px0 + i * 16 + l16;
        int n = px / 400;
        int rem = px - n * 400;
        int oy = rem / 20;
        int ox = rem - oy * 20;
        abase[i] = x + (long)n * 28224 + quad * 7056 + oy * 4 * 84 + ox * 4;
    }
    f32x4 acc[4][2];
#pragma unroll
    for (int i = 0; i < 4; i++)
#pragma unroll
        for (int j = 0; j < 2; j++)
#pragma unroll
            for (int r = 0; r < 4; r++) acc[i][j][r] = 0.f;
    float4 cur[8];
#pragma unroll
    for (int i = 0; i < 4; i++) {
        cur[i * 2] = *(const float4*)abase[i];
        cur[i * 2 + 1] = *(const float4*)(abase[i] + 4);
    }
#pragma unroll
    for (int ky = 0; ky < 8; ky++) {
        float4 nxt[8];
        if (ky < 7) {
#pragma unroll
            for (int i = 0; i < 4; i++) {
                const float* p = abase[i] + (ky + 1) * 84;
                nxt[i * 2] = *(const float4*)p;
                nxt[i * 2 + 1] = *(const float4*)(p + 4);
            }
        }
        int wo = (ky * 32 + l16) * 32 + quad * 8;
        bf16x8 bh0 = *(const bf16x8*)(wbh + wo);
        bf16x8 bh1 = *(const bf16x8*)(wbh + wo + 512);
        bf16x8 bl0 = *(const bf16x8*)(wbl + wo);
        bf16x8 bl1 = *(const bf16x8*)(wbl + wo + 512);
        bf16x8 ah[4], al[4];
#pragma unroll
        for (int i = 0; i < 4; i++) {
            float v[8] = {cur[i * 2].x, cur[i * 2].y, cur[i * 2].z, cur[i * 2].w,
                          cur[i * 2 + 1].x, cur[i * 2 + 1].y, cur[i * 2 + 1].z, cur[i * 2 + 1].w};
#pragma unroll
            for (int j = 0; j < 8; j++) {
                short hh, ll;
                split_trunc(v[j], hh, ll);
                ah[i][j] = hh;
                al[i][j] = ll;
            }
        }
#pragma unroll
        for (int i = 0; i < 4; i++) {
            acc[i][0] = __builtin_amdgcn_mfma_f32_16x16x32_bf16(ah[i], bh0, acc[i][0], 0, 0, 0);
            acc[i][0] = __builtin_amdgcn_mfma_f32_16x16x32_bf16(al[i], bh0, acc[i][0], 0, 0, 0);
            acc[i][0] = __builtin_amdgcn_mfma_f32_16x16x32_bf16(ah[i], bl0, acc[i][0], 0, 0, 0);
            acc[i][1] = __builtin_amdgcn_mfma_f32_16x16x32_bf16(ah[i], bh1, acc[i][1], 0, 0, 0);
            acc[i][1] = __builtin_amdgcn_mfma_f32_16x16x32_bf16(al[i], bh1, acc[i][1], 0, 0, 0);
            acc[i][1] = __builtin_amdgcn_mfma_f32_16x16x32_bf16(ah[i], bl1, acc[i][1], 0, 0, 0);
        }
        if (ky < 7) {
#pragma unroll
            for (int q = 0; q < 8; q++) cur[q] = nxt[q];
        }
    }
    float bias0 = b1[l16], bias1 = b1[16 + l16];
#pragma unroll
    for (int i = 0; i < 4; i++) {
#pragma unroll
        for (int r = 0; r < 4; r++) {
            long px = px0 + i * 16 + quad * 4 + r;
            long o = px * 32;
            float v0 = fmaxf(acc[i][0][r] + bias0, 0.f);
            float v1 = fmaxf(acc[i][1][r] + bias1, 0.f);
            short h0, l0, h1, l1;
            split_trunc(v0, h0, l0);
            split_trunc(v1, h1, l1);
            yhi[o + l16] = (unsigned short)h0;
            ylo[o + l16] = (unsigned short)l0;
            yhi[o + 16 + l16] = (unsigned short)h1;
            ylo[o + 16 + l16] = (unsigned short)l1;
        }
    }
}

// ============ conv2/3: LDS-free implicit-GEMM, 1 wave per block, 64px x 64ch ============
template <int C, int IH, int IW, int OH, int OW, int S, int KH, int KW>
__global__ __launch_bounds__(64, 3) void convm_k(
    const unsigned short* __restrict__ xhi, const unsigned short* __restrict__ xlo,
    const unsigned short* __restrict__ whi, const unsigned short* __restrict__ wlo,
    const float* __restrict__ bias,
    unsigned short* __restrict__ yhi, unsigned short* __restrict__ ylo) {
    constexpr int CH = C / 32;
    constexpr int NCHUNK = KH * KW * CH;
    int lane = threadIdx.x, l16 = lane & 15, quad = lane >> 4;
    int pxbase = blockIdx.x * 64;
    long xoff[4];
#pragma unroll
    for (int i = 0; i < 4; i++) {
        int px = pxbase + i * 16 + l16;
        int n = px / (OH * OW);
        int rem = px - n * (OH * OW);
        int oy = rem / OW;
        int ox = rem - oy * OW;
        xoff[i] = (((long)n * IH + oy * S) * IW + ox * S) * C + quad * 8;
    }
    f32x4 acc[4][4];
#pragma unroll
    for (int i = 0; i < 4; i++)
#pragma unroll
        for (int j = 0; j < 4; j++)
#pragma unroll
            for (int r = 0; r < 4; r++) acc[i][j][r] = 0.f;
#pragma unroll 2
    for (int ck = 0; ck < NCHUNK; ck++) {
        int kyx = ck / CH;
        int ch = ck - kyx * CH;
        int ky = kyx / KW, kx = kyx - ky * KW;
        long koff = ((long)(ky * IW + kx)) * C + ch * 32;
        bf16x8 ah[4], al[4], bh[4], bl[4];
#pragma unroll
        for (int i = 0; i < 4; i++) {
            ah[i] = *(const bf16x8*)(xhi + xoff[i] + koff);
            al[i] = *(const bf16x8*)(xlo + xoff[i] + koff);
        }
#pragma unroll
        for (int j = 0; j < 4; j++) {
            long b = ((long)ck * 64 + j * 16 + l16) * 32 + quad * 8;
            bh[j] = *(const bf16x8*)(whi + b);
            bl[j] = *(const bf16x8*)(wlo + b);
        }
#pragma unroll
        for (int i = 0; i < 4; i++)
#pragma unroll
            for (int j = 0; j < 4; j++) {
                acc[i][j] = __builtin_amdgcn_mfma_f32_16x16x32_bf16(ah[i], bh[j], acc[i][j], 0, 0, 0);
                acc[i][j] = __builtin_amdgcn_mfma_f32_16x16x32_bf16(ah[i], bl[j], acc[i][j], 0, 0, 0);
                acc[i][j] = __builtin_amdgcn_mfma_f32_16x16x32_bf16(al[i], bh[j], acc[i][j], 0, 0, 0);
            }
    }
#pragma unroll
    for (int i = 0; i < 4; i++)
#pragma unroll
        for (int j = 0; j < 4; j++) {
            int col = j * 16 + l16;
            float bv = bias[col];
#pragma unroll
            for (int r = 0; r < 4; r++) {
                int prow = pxbase + i * 16 + quad * 4 + r;
                float v = fmaxf(acc[i][j][r] + bv, 0.f);
                unsigned short h = f2b(v);
                yhi[(long)prow * 64 + col] = h;
                ylo[(long)prow * 64 + col] = f2b(v - b2f(h));
            }
        }
}

// ============ fc: LDS-free split-bf16 MFMA, 1 wave per block, K-split x7 ============
__global__ __launch_bounds__(64, 3) void fc_k(
    const unsigned short* __restrict__ Ahi, const unsigned short* __restrict__ Alo,
    const unsigned short* __restrict__ Bhi, const unsigned short* __restrict__ Blo,
    float* __restrict__ Cp) {
    int lane = threadIdx.x, l16 = lane & 15, quad = lane >> 4;
    int m0 = blockIdx.x * 64, n0 = blockIdx.y * 64;
    int z = blockIdx.z;
    int kBase = z * 448;
    f32x4 acc[4][4];
#pragma unroll
    for (int i = 0; i < 4; i++)
#pragma unroll
        for (int j = 0; j < 4; j++)
#pragma unroll
            for (int r = 0; r < 4; r++) acc[i][j][r] = 0.f;
#pragma unroll 2
    for (int k0 = kBase; k0 < kBase + 448; k0 += 32) {
        bf16x8 ah[4], al[4], bh[4], bl[4];
#pragma unroll
        for (int i = 0; i < 4; i++) {
            long a = (long)(m0 + i * 16 + l16) * 3136 + k0 + quad * 8;
            ah[i] = *(const bf16x8*)(Ahi + a);
            al[i] = *(const bf16x8*)(Alo + a);
        }
#pragma unroll
        for (int j = 0; j < 4; j++) {
            long b = (long)(n0 + j * 16 + l16) * 3136 + k0 + quad * 8;
            bh[j] = *(const bf16x8*)(Bhi + b);
            bl[j] = *(const bf16x8*)(Blo + b);
        }
#pragma unroll
        for (int i = 0; i < 4; i++)
#pragma unroll
            for (int j = 0; j < 4; j++) {
                acc[i][j] = __builtin_amdgcn_mfma_f32_16x16x32_bf16(ah[i], bh[j], acc[i][j], 0, 0, 0);
                acc[i][j] = __builtin_amdgcn_mfma_f32_16x16x32_bf16(ah[i], bl[j], acc[i][j], 0, 0, 0);
                acc[i][j] = __builtin_amdgcn_mfma_f32_16x16x32_bf16(al[i], bh[j], acc[i][j], 0, 0, 0);
            }
    }
    float* Cz = Cp + (long)z * 1048576;
#pragma unroll
    for (int i = 0; i < 4; i++)
#pragma unroll
        for (int j = 0; j < 4; j++) {
            int col = n0 + j * 16 + l16;
#pragma unroll
            for (int r = 0; r < 4; r++) {
                int row = m0 + i * 16 + quad * 4 + r;
                Cz[row * 512 + col] = acc[i][j][r];
            }
        }
}

// ============ fc finalize: sum 7 partials + bias + relu ============
__global__ __launch_bounds__(256) void fc_fin(
    const float* __restrict__ Cp, const float* __restrict__ bias,
    float* __restrict__ f, unsigned short* __restrict__ fb) {
    int tid = blockIdx.x * 256 + threadIdx.x;
    int col = tid & 511;
    float v = bias[col];
#pragma unroll
    for (int z = 0; z < 7; z++) v += Cp[tid + (long)z * 1048576];
    v = fmaxf(v, 0.f);
    f[tid] = v;
    fb[tid] = f2b(v);
}

// ============ gate ============
__global__ __launch_bounds__(256) void gate_k(
    const float* __restrict__ f, const float* __restrict__ gw, const float* __restrict__ gb,
    int* __restrict__ topi, float* __restrict__ topp) {
    int wave = threadIdx.x >> 6, lane = threadIdx.x & 63;
    int row = blockIdx.x * 4 + wave;
    float fv[8];
#pragma unroll
    for (int j = 0; j < 8; j++) fv[j] = f[row * 512 + lane + 64 * j];
    float lg[6];
#pragma unroll
    for (int e = 0; e < 6; e++) {
        float a = 0.f;
#pragma unroll
        for (int j = 0; j < 8; j++) a += fv[j] * gw[(lane + 64 * j) * 6 + e];
#pragma unroll
        for (int off = 32; off > 0; off >>= 1) a += __shfl_xor(a, off, 64);
        lg[e] = a + gb[e];
    }
    if (lane == 0) {
        int i1 = 0;
        float v1 = lg[0];
#pragma unroll
        for (int e = 1; e < 6; e++)
            if (lg[e] > v1) { v1 = lg[e]; i1 = e; }
        int i2 = (i1 == 0) ? 1 : 0;
        float v2 = lg[i2];
#pragma unroll
        for (int e = 0; e < 6; e++)
            if (e != i1 && lg[e] > v2) { v2 = lg[e]; i2 = e; }
        float pa = 1.f / (1.f + expf(v2 - v1));
        topi[row * 2] = i1;
        topi[row * 2 + 1] = i2;
        topp[row * 2] = pa;
        topp[row * 2 + 1] = 1.f - pa;
    }
}

// ============ expert GEMM: LDS-free bf16 MFMA, 1 wave per block, 64x64 tile ============
__global__ __launch_bounds__(64, 4) void moe_gemm(
    const unsigned short* __restrict__ A, long aStride,
    const unsigned short* __restrict__ Bt, const float* __restrict__ bias,
    unsigned short* __restrict__ C) {
    int e = blockIdx.z;
    const unsigned short* Ae = A + (long)e * aStride;
    const unsigned short* Be = Bt + (long)e * 262144;
    const float* be = bias + e * 512;
    unsigned short* Ce = C + (long)e * 2048 * 512;
    int lane = threadIdx.x, l16 = lane & 15, quad = lane >> 4;
    int m0 = blockIdx.x * 64, n0 = blockIdx.y * 64;
    f32x4 acc[4][4];
#pragma unroll
    for (int i = 0; i < 4; i++)
#pragma unroll
        for (int j = 0; j < 4; j++)
#pragma unroll
            for (int r = 0; r < 4; r++) acc[i][j][r] = 0.f;
#pragma unroll 4
    for (int k0 = 0; k0 < 512; k0 += 32) {
        bf16x8 a[4], b[4];
#pragma unroll
        for (int i = 0; i < 4; i++)
            a[i] = *(const bf16x8*)(Ae + (long)(m0 + i * 16 + l16) * 512 + k0 + quad * 8);
#pragma unroll
        for (int j = 0; j < 4; j++)
            b[j] = *(const bf16x8*)(Be + (long)(n0 + j * 16 + l16) * 512 + k0 + quad * 8);
#pragma unroll
        for (int i = 0; i < 4; i++)
#pragma unroll
            for (int j = 0; j < 4; j++)
                acc[i][j] = __builtin_amdgcn_mfma_f32_16x16x32_bf16(a[i], b[j], acc[i][j], 0, 0, 0);
    }
#pragma unroll
    for (int i = 0; i < 4; i++)
#pragma unroll
        for (int j = 0; j < 4; j++) {
            int col = n0 + j * 16 + l16;
            float bcol = be[col];
#pragma unroll
            for (int r = 0; r < 4; r++) {
                int row = m0 + i * 16 + quad * 4 + r;
                float v = fmaxf(acc[i][j][r] + bcol, 0.f);
                Ce[(long)row * 512 + col] = f2b(v);
            }
        }
}

// ============ combine: wave per row, coalesced, shuffle-reduce ============
__global__ __launch_bounds__(256) void combine_k(
    const unsigned short* __restrict__ h2, const float* __restrict__ w3t,
    const float* __restrict__ b3, const int* __restrict__ topi,
    const float* __restrict__ topp, float* __restrict__ out) {
    int b = blockIdx.x * 4 + (threadIdx.x >> 6);
    int lane = threadIdx.x & 63;
    int e0 = topi[b * 2], e1 = topi[b * 2 + 1];
    float p0 = topp[b * 2], p1 = topp[b * 2 + 1];
    float r[12];
#pragma unroll
    for (int a = 0; a < 12; a++) r[a] = 0.f;
#pragma unroll
    for (int j = 0; j < 2; j++) {
        int e = j ? e1 : e0;
        float p = j ? p1 : p0;
        const unsigned short* hp = h2 + ((long)e * 2048 + b) * 512 + lane * 8;
        bf16x8 hv = *(const bf16x8*)hp;
        float hf[8];
#pragma unroll
        for (int q = 0; q < 8; q++) hf[q] = b2f((unsigned short)hv[q]);
        const float* wb = w3t + e * 6144 + lane * 8;
#pragma unroll
        for (int a = 0; a < 12; a++) {
            float4 w0 = *(const float4*)(wb + a * 512);
            float4 w1 = *(const float4*)(wb + a * 512 + 4);
            float acc = hf[0] * w0.x + hf[1] * w0.y + hf[2] * w0.z + hf[3] * w0.w +
                        hf[4] * w1.x + hf[5] * w1.y + hf[6] * w1.z + hf[7] * w1.w;
            r[a] += p * acc;
        }
    }
#pragma unroll
    for (int a = 0; a < 12; a++)
#pragma unroll
        for (int off = 32; off > 0; off >>= 1) r[a] += __shfl_xor(r[a], off, 64);
    float v = 0.f;
#pragma unroll
    for (int a = 0; a < 12; a++)
        if (lane == a) v = r[a];
    if (lane < 12)
        out[b * 12 + lane] = v + p0 * b3[e0 * 12 + lane] + p1 * b3[e1 * 12 + lane];
}

extern "C" void kernel_launch(void* const* d_in, const int* in_sizes, int n_in,
                              void* d_out, int out_size, void* d_ws, size_t ws_size,
                              hipStream_t stream) {
    const float* x   = (const float*)d_in[0];
    const float* c1w = (const float*)d_in[1];
    const float* c1b = (const float*)d_in[2];
    const float* c2w = (const float*)d_in[3];
    const float* c2b = (const float*)d_in[4];
    const float* c3w = (const float*)d_in[5];
    const float* c3b = (const float*)d_in[6];
    const float* fcw = (const float*)d_in[7];
    const float* fcb = (const float*)d_in[8];
    const float* gw  = (const float*)d_in[9];
    const float* gb  = (const float*)d_in[10];
    const float* ew1 = (const float*)d_in[11];
    const float* eb1 = (const float*)d_in[12];
    const float* ew2 = (const float*)d_in[13];
    const float* eb2 = (const float*)d_in[14];
    const float* ew3 = (const float*)d_in[15];
    const float* eb3 = (const float*)d_in[16];

    char* ws = (char*)d_ws;
    unsigned short* y1hi = (unsigned short*)(ws + 0L);          // 52428800 B
    unsigned short* y1lo = (unsigned short*)(ws + 52428800L);   // 52428800 B
    unsigned short* f3hi = (unsigned short*)(ws + 0L);          // alias (y1 dead after conv2)
    unsigned short* f3lo = (unsigned short*)(ws + 12845056L);   // alias
    unsigned short* y2hi = (unsigned short*)(ws + 104857600L);  // 21233664 B
    unsigned short* y2lo = (unsigned short*)(ws + 126091264L);  // 21233664 B
    unsigned short* h1   = (unsigned short*)(ws + 104857600L);  // alias (y2 dead after conv3)
    unsigned short* h2   = (unsigned short*)(ws + 117440512L);  // alias
    float* f             = (float*)(ws + 147324928L);           // 4194304 B
    unsigned short* fb   = (unsigned short*)(ws + 151519232L);  // 2097152 B
    int*   topi          = (int*)(ws + 153616384L);             // 16384 B
    float* topp          = (float*)(ws + 153632768L);           // 16384 B
    unsigned short* w2h  = (unsigned short*)(ws + 153681920L);  // 65536 B
    unsigned short* w2l  = (unsigned short*)(ws + 153747456L);  // 65536 B
    unsigned short* w3h  = (unsigned short*)(ws + 153812992L);  // 73728 B
    unsigned short* w3l  = (unsigned short*)(ws + 153886720L);  // 73728 B
    unsigned short* fcwh = (unsigned short*)(ws + 153960448L);  // 3211264 B
    unsigned short* fcwl = (unsigned short*)(ws + 157171712L);  // 3211264 B
    unsigned short* ew1t = (unsigned short*)(ws + 160382976L);  // 3145728 B
    unsigned short* ew2t = (unsigned short*)(ws + 163528704L);  // 3145728 B
    float* w3t           = (float*)(ws + 166674432L);           // 147456 B
    float* Cp            = (float*)(ws + 166821888L);           // 7*4194304 = 29360128 B
    unsigned short* wb1h = (unsigned short*)(ws + 196182016L);  // 16384 B
    unsigned short* wb1l = (unsigned short*)(ws + 196198400L);  // 16384 B (end 196214784)
    float* out = (float*)d_out;

    hipLaunchKernelGGL(prep_w, dim3(448), dim3(256), 0, stream, c1w, c2w, c3w, ew3,
                       wb1h, wb1l, w2h, w2l, w3h, w3l, w3t);
    hipLaunchKernelGGL(prep_fcw, dim3(49, 8), dim3(256), 0, stream, fcw, fcwh, fcwl);
    hipLaunchKernelGGL(prep_ewT, dim3(16, 16, 12), dim3(32, 8), 0, stream, ew1, ew2, ew1t, ew2t);
    hipLaunchKernelGGL(conv1_k, dim3(3200), dim3(256), 0, stream, x, wb1h, wb1l, c1b, y1hi, y1lo);
    hipLaunchKernelGGL((convm_k<32, 20, 20, 9, 9, 2, 4, 4>), dim3(2592), dim3(64), 0, stream,
                       y1hi, y1lo, w2h, w2l, c2b, y2hi, y2lo);
    hipLaunchKernelGGL((convm_k<64, 9, 9, 7, 7, 1, 3, 3>), dim3(1568), dim3(64), 0, stream,
                       y2hi, y2lo, w3h, w3l, c3b, f3hi, f3lo);
    hipLaunchKernelGGL(fc_k, dim3(32, 8, 7), dim3(64), 0, stream, f3hi, f3lo, fcwh, fcwl, Cp);
    hipLaunchKernelGGL(fc_fin, dim3(4096), dim3(256), 0, stream, Cp, fcb, f, fb);
    hipLaunchKernelGGL(gate_k, dim3(512), dim3(256), 0, stream, f, gw, gb, topi, topp);
    hipLaunchKernelGGL(moe_gemm, dim3(32, 8, 6), dim3(64), 0, stream, fb, 0L, ew1t, eb1, h1);
    hipLaunchKernelGGL(moe_gemm, dim3(32, 8, 6), dim3(64), 0, stream, h1, 1048576L, ew2t, eb2, h2);
    hipLaunchKernelGGL(combine_k, dim3(512), dim3(256), 0, stream, h2, w3t, eb3, topi, topp, out);
}